// Round 15
// baseline (487.879 us; speedup 1.0000x reference)
//
#include <hip/hip_runtime.h>

#define NROWS   16384
#define INDIM   1024
#define KDIM    256
#define NCODES  4096
#define G_ROWS  32       // rows per fallback-gemm block
#define V_ROWS  64       // rows per fallback vq / merge block
#define P_ROWS  128      // rows per vq_partial block
#define PSTEP   64       // vq_partial: steps of 16 codes (quarter = 1024 codes)
#define NSTEP   128      // full-scan vq fallback: steps of 32 codes

// vq_partial LDS: 2 buffers x (hi 8KB + lo 8KB) = 32 KB -> 4 blocks/CU
#define PVBUF   16384
// fallback vq LDS: 2 buffers x (hi 16KB + lo 16KB)
#define VBUF    32768

// gemm LDS: X 3x8KB ([s][rs][lane]) + W 3x32KB ([s][cidx][lane])
#define MG_ROWS 64
#define MG_KC   64
#define MG_NCH  (INDIM / MG_KC)   // 16
#define XP(p)   ((p) * 8192)
#define WP(p)   (24576 + (p) * 32768)
#define MG_LDS  122880

typedef float f32x4 __attribute__((ext_vector_type(4)));
typedef int   i32x2 __attribute__((ext_vector_type(2)));
typedef short short8 __attribute__((ext_vector_type(8)));
typedef unsigned short u16x8 __attribute__((ext_vector_type(8)));
typedef unsigned short u16x4 __attribute__((ext_vector_type(4)));

__device__ inline unsigned short f2bf(float f) {
    unsigned u = __builtin_bit_cast(unsigned, f);
    u = (u + 0x7fffu + ((u >> 16) & 1u)) >> 16;
    return (unsigned short)u;
}
__device__ inline float bf2f(unsigned short h) {
    unsigned u = ((unsigned)h) << 16;
    return __builtin_bit_cast(float, u);
}
__device__ inline f32x4 mfma16(u16x8 a, u16x8 b, f32x4 c) {
    return __builtin_amdgcn_mfma_f32_16x16x32_bf16(
        __builtin_bit_cast(short8, a), __builtin_bit_cast(short8, b), c, 0, 0, 0);
}

// async global->LDS DMA, 16B/lane; dest = wave-uniform base + lane*16 (HW-implicit)
__device__ inline void gload16(const void* g, void* l) {
    __builtin_amdgcn_global_load_lds(
        (const __attribute__((address_space(1))) unsigned int*)g,
        (__attribute__((address_space(3))) unsigned int*)l,
        16, 0, 0);
}

// ---------------- prep: W[1024][256] f32 -> W_T 3-way bf16 split [256][1024] ----------------
__global__ __launch_bounds__(256) void wprep_kernel(const float* __restrict__ W,
                                                    unsigned short* __restrict__ wt_hi,
                                                    unsigned short* __restrict__ wt_md,
                                                    unsigned short* __restrict__ wt_lo) {
    const int t = threadIdx.x;
    const int k = blockIdx.x * 4 + (t >> 6);
    const int c0 = (t & 63) * 4;
    f32x4 v = *(const f32x4*)(W + (size_t)k * KDIM + c0);
    #pragma unroll
    for (int i = 0; i < 4; ++i) {
        const unsigned short h = f2bf(v[i]);
        const float r1 = v[i] - bf2f(h);
        const unsigned short m = f2bf(r1);
        const unsigned short lo = f2bf(r1 - bf2f(m));
        wt_hi[(size_t)(c0 + i) * INDIM + k] = h;
        wt_md[(size_t)(c0 + i) * INDIM + k] = m;
        wt_lo[(size_t)(c0 + i) * INDIM + k] = lo;
    }
}

// ---------------- MFMA gemm: h = x@W + b (6-pass 3-way split, f32-class accuracy) ----------------
__global__ __launch_bounds__(256, 1) void gemm_mfma_kernel(const float* __restrict__ x,
                                                           const unsigned short* __restrict__ wt_hi,
                                                           const unsigned short* __restrict__ wt_md,
                                                           const unsigned short* __restrict__ wt_lo,
                                                           const float* __restrict__ bvec,
                                                           float* __restrict__ hbuf) {
    __shared__ __align__(16) char lds[MG_LDS];

    const int t  = threadIdx.x;
    const int w  = t >> 6;
    const int l  = t & 63;
    const int nl = l & 15;
    const int g  = l >> 4;
    const size_t n0 = (size_t)blockIdx.x * MG_ROWS;
    const int lb = l * 16;

    f32x4 acc[4][4];
    #pragma unroll
    for (int a = 0; a < 4; ++a)
        #pragma unroll
        for (int b = 0; b < 4; ++b) acc[a][b] = (f32x4){0.f, 0.f, 0.f, 0.f};

    for (int kc = 0; kc < MG_NCH; ++kc) {
        f32x4 xa[2], xb[2];
        #pragma unroll
        for (int c = 0; c < 2; ++c) {
            const int idx = w * 2 + c;
            const int sX = idx >> 2, rsX = idx & 3;
            const float* p = x + (n0 + rsX * 16 + nl) * INDIM + kc * MG_KC + sX * 32 + g * 8;
            xa[c] = *(const f32x4*)(p);
            xb[c] = *(const f32x4*)(p + 4);
        }
        u16x8 wh[8], wm[8], wl[8];
        #pragma unroll
        for (int ci = 0; ci < 4; ++ci)
            #pragma unroll
            for (int sW = 0; sW < 2; ++sW) {
                const int q = ci * 2 + sW;
                const size_t off = (size_t)((w * 4 + ci) * 16 + nl) * INDIM
                                 + kc * MG_KC + sW * 32 + g * 8;
                wh[q] = *(const u16x8*)(wt_hi + off);
                wm[q] = *(const u16x8*)(wt_md + off);
                wl[q] = *(const u16x8*)(wt_lo + off);
            }
        __syncthreads();

        #pragma unroll
        for (int c = 0; c < 2; ++c) {
            const int idx = w * 2 + c;
            const int sX = idx >> 2, rsX = idx & 3;
            u16x8 xh, xm, xl;
            #pragma unroll
            for (int e = 0; e < 4; ++e) {
                const float a0 = xa[c][e], a1 = xb[c][e];
                const unsigned short h0 = f2bf(a0);
                const float r10 = a0 - bf2f(h0);
                const unsigned short m0 = f2bf(r10);
                const unsigned short l0 = f2bf(r10 - bf2f(m0));
                const unsigned short h1 = f2bf(a1);
                const float r11 = a1 - bf2f(h1);
                const unsigned short m1 = f2bf(r11);
                const unsigned short l1 = f2bf(r11 - bf2f(m1));
                xh[e] = h0; xh[4+e] = h1;
                xm[e] = m0; xm[4+e] = m1;
                xl[e] = l0; xl[4+e] = l1;
            }
            const int base = (sX * 4 + rsX) * 1024 + lb;
            *(u16x8*)(lds + XP(0) + base) = xh;
            *(u16x8*)(lds + XP(1) + base) = xm;
            *(u16x8*)(lds + XP(2) + base) = xl;
        }
        #pragma unroll
        for (int ci = 0; ci < 4; ++ci)
            #pragma unroll
            for (int sW = 0; sW < 2; ++sW) {
                const int q = ci * 2 + sW;
                const int base = (sW * 16 + w * 4 + ci) * 1024 + lb;
                *(u16x8*)(lds + WP(0) + base) = wh[q];
                *(u16x8*)(lds + WP(1) + base) = wm[q];
                *(u16x8*)(lds + WP(2) + base) = wl[q];
            }
        __syncthreads();

        #pragma unroll
        for (int s = 0; s < 2; ++s) {
            u16x8 bh[4], bm[4], bl[4], ah[4], am[4], al[4];
            #pragma unroll
            for (int rs = 0; rs < 4; ++rs) {
                const int base = (s * 4 + rs) * 1024 + lb;
                bh[rs] = *(const u16x8*)(lds + XP(0) + base);
                bm[rs] = *(const u16x8*)(lds + XP(1) + base);
                bl[rs] = *(const u16x8*)(lds + XP(2) + base);
            }
            #pragma unroll
            for (int ct = 0; ct < 4; ++ct) {
                const int base = (s * 16 + w * 4 + ct) * 1024 + lb;
                ah[ct] = *(const u16x8*)(lds + WP(0) + base);
                am[ct] = *(const u16x8*)(lds + WP(1) + base);
                al[ct] = *(const u16x8*)(lds + WP(2) + base);
            }
            #pragma unroll
            for (int ct = 0; ct < 4; ++ct)
                #pragma unroll
                for (int rs = 0; rs < 4; ++rs) {
                    acc[ct][rs] = mfma16(ah[ct], bh[rs], acc[ct][rs]);
                    acc[ct][rs] = mfma16(ah[ct], bm[rs], acc[ct][rs]);
                    acc[ct][rs] = mfma16(am[ct], bh[rs], acc[ct][rs]);
                    acc[ct][rs] = mfma16(ah[ct], bl[rs], acc[ct][rs]);
                    acc[ct][rs] = mfma16(al[ct], bh[rs], acc[ct][rs]);
                    acc[ct][rs] = mfma16(am[ct], bm[rs], acc[ct][rs]);
                }
        }
    }

    #pragma unroll
    for (int ct = 0; ct < 4; ++ct) {
        float bv[4];
        #pragma unroll
        for (int r = 0; r < 4; ++r) bv[r] = bvec[w * 64 + ct * 16 + g * 4 + r];
        #pragma unroll
        for (int rs = 0; rs < 4; ++rs) {
            const size_t row = n0 + rs * 16 + nl;
            #pragma unroll
            for (int r = 0; r < 4; ++r)
                hbuf[row * KDIM + w * 64 + ct * 16 + g * 4 + r] = acc[ct][rs][r] + bv[r];
        }
    }
}

// ---------------- fallback f32 gemm ----------------
__global__ __launch_bounds__(256, 2) void gemm_fb_kernel(const float* __restrict__ x,
                                                         const float* __restrict__ W,
                                                         const float* __restrict__ bvec,
                                                         float* __restrict__ hbuf) {
    const int t  = threadIdx.x;
    const int cg = t & 15;
    const int rg = t >> 4;
    const size_t n0 = (size_t)blockIdx.x * G_ROWS;
    const int c0 = cg * 16;

    float acc[2][16];
    #pragma unroll
    for (int j = 0; j < 2; ++j)
        #pragma unroll
        for (int cc = 0; cc < 16; ++cc) acc[j][cc] = 0.f;

    for (int k4 = 0; k4 < INDIM / 4; ++k4) {
        const int k = k4 * 4;
        f32x4 xv[2];
        #pragma unroll
        for (int j = 0; j < 2; ++j)
            xv[j] = *(const f32x4*)(x + (n0 + rg + 16 * j) * INDIM + k);
        f32x4 wv[4][4];
        #pragma unroll
        for (int kk = 0; kk < 4; ++kk)
            #pragma unroll
            for (int q = 0; q < 4; ++q)
                wv[kk][q] = *(const f32x4*)(W + (size_t)(k + kk) * KDIM + c0 + 4 * q);
        #pragma unroll
        for (int j = 0; j < 2; ++j)
            #pragma unroll
            for (int kk = 0; kk < 4; ++kk) {
                const float xs = xv[j][kk];
                #pragma unroll
                for (int q = 0; q < 4; ++q)
                    #pragma unroll
                    for (int e = 0; e < 4; ++e)
                        acc[j][4*q+e] = fmaf(xs, wv[kk][q][e], acc[j][4*q+e]);
            }
    }
    #pragma unroll
    for (int j = 0; j < 2; ++j) {
        float* dst = hbuf + (n0 + rg + 16 * j) * KDIM + c0;
        #pragma unroll
        for (int q = 0; q < 4; ++q) {
            f32x4 v;
            #pragma unroll
            for (int e = 0; e < 4; ++e) v[e] = acc[j][4*q+e] + bvec[c0 + 4*q + e];
            *(f32x4*)(dst + 4*q) = v;
        }
    }
}

// ---------------- prep: cnorm + optional bf16 hi/lo split of cb ----------------
__global__ __launch_bounds__(256) void prep_kernel(const float* __restrict__ cb,
                                                   float* __restrict__ cnorm,
                                                   unsigned short* __restrict__ cb_hi,
                                                   unsigned short* __restrict__ cb_lo,
                                                   int do_split) {
    const int c    = blockIdx.x * 4 + (threadIdx.x >> 6);
    const int lane = threadIdx.x & 63;
    f32x4 v = ((const f32x4*)(cb + (size_t)c * KDIM))[lane];
    if (do_split) {
        u16x4 h4, l4;
        #pragma unroll
        for (int j = 0; j < 4; ++j) {
            unsigned short h = f2bf(v[j]);
            h4[j] = h;
            l4[j] = f2bf(v[j] - bf2f(h));
        }
        *(u16x4*)(cb_hi + (size_t)c * KDIM + lane * 4) = h4;
        *(u16x4*)(cb_lo + (size_t)c * KDIM + lane * 4) = l4;
    }
    float s = v[0]*v[0] + v[1]*v[1] + v[2]*v[2] + v[3]*v[3];
    #pragma unroll
    for (int off = 1; off < 64; off <<= 1) s += __shfl_xor(s, off);
    if (lane == 0) cnorm[c] = s;
}

// ===== vq partial: 128 rows/block, quarter of codes, 16 codes/step, 4 blocks/CU =============
template<int PRE>
__global__ __launch_bounds__(256, 4) void vq_partial_kernel(
    const float* __restrict__ hbuf,
    const float* __restrict__ cb,
    const float* __restrict__ cnorm,
    const unsigned short* __restrict__ cb_hi,
    const unsigned short* __restrict__ cb_lo,
    int* __restrict__ recs)                    // [NROWS][4] int2 {i1,i2}
{
    __shared__ __align__(16) char lds[2 * PVBUF];   // 32 KB

    const int t  = threadIdx.x;
    const int w  = t >> 6;
    const int l  = t & 63;
    const int nl = l & 15;
    const int g  = l >> 4;
    const int lb = l * 16;
    const int bid  = blockIdx.x;
    const int quar = bid & 3;
    const int cbase = quar * 1024;
    const size_t n0 = (size_t)(bid >> 2) * P_ROWS;

    // B-fragments for 2 row-sets: rows w*32 + rset*16 + nl
    u16x8 bhi[2][8], bmid[2][8];
    #pragma unroll
    for (int rset = 0; rset < 2; ++rset) {
        const float* hrow = hbuf + (n0 + w * 32 + rset * 16 + nl) * KDIM;
        #pragma unroll
        for (int s = 0; s < 8; ++s) {
            f32x4 a = *(const f32x4*)(hrow + s * 32 + g * 8);
            f32x4 b = *(const f32x4*)(hrow + s * 32 + g * 8 + 4);
            u16x8 uh, um;
            #pragma unroll
            for (int jj = 0; jj < 4; ++jj) {
                unsigned short h0 = f2bf(a[jj]); uh[jj]   = h0; um[jj]   = f2bf(a[jj] - bf2f(h0));
                unsigned short h1 = f2bf(b[jj]); uh[4+jj] = h1; um[4+jj] = f2bf(b[jj] - bf2f(h1));
            }
            bhi[rset][s] = uh; bmid[rset][s] = um;
        }
    }

    float v1[2] = {3.4e38f, 3.4e38f}, v2[2] = {3.4e38f, 3.4e38f};
    int   i1[2] = {0, 0},            i2[2] = {0, 0};

    u16x8 rh[2], rl[2];   // non-PRE only

    // ---- prologue: stage step 0 into buffer 0; wave w covers chunks sc = w*2, w*2+1 ----
    if (PRE) {
        #pragma unroll
        for (int sv = 0; sv < 2; ++sv) {
            const int sc = w * 2 + sv;
            const size_t off = (size_t)(cbase + nl) * KDIM + (sc * 4 + g) * 8;
            gload16(cb_hi + off, lds + sc * 1024);
            gload16(cb_lo + off, lds + 8192 + sc * 1024);
        }
    } else {
        #pragma unroll
        for (int sv = 0; sv < 2; ++sv) {
            const int sc = w * 2 + sv;
            const float* p = cb + (size_t)(cbase + nl) * KDIM + (sc * 4 + g) * 8;
            f32x4 a = *(const f32x4*)(p);
            f32x4 b = *(const f32x4*)(p + 4);
            u16x8 uh, ul;
            #pragma unroll
            for (int jj = 0; jj < 4; ++jj) {
                unsigned short h0 = f2bf(a[jj]); uh[jj]   = h0; ul[jj]   = f2bf(a[jj] - bf2f(h0));
                unsigned short h1 = f2bf(b[jj]); uh[4+jj] = h1; ul[4+jj] = f2bf(b[jj] - bf2f(h1));
            }
            rh[sv] = uh; rl[sv] = ul;
        }
        #pragma unroll
        for (int sv = 0; sv < 2; ++sv) {
            const int sc = w * 2 + sv;
            *(u16x8*)(lds + sc * 1024 + lb) = rh[sv];
            *(u16x8*)(lds + 8192 + sc * 1024 + lb) = rl[sv];
        }
    }
    __syncthreads();

    for (int S = 0; S < PSTEP; ++S) {
        const int b = S & 1;
        char* nbuf = lds + (b ^ 1) * PVBUF;
        if (S + 1 < PSTEP) {
            if (PRE) {
                #pragma unroll
                for (int sv = 0; sv < 2; ++sv) {
                    const int sc = w * 2 + sv;
                    const size_t off = (size_t)(cbase + (S + 1) * 16 + nl) * KDIM + (sc * 4 + g) * 8;
                    gload16(cb_hi + off, nbuf + sc * 1024);
                    gload16(cb_lo + off, nbuf + 8192 + sc * 1024);
                }
            } else {
                #pragma unroll
                for (int sv = 0; sv < 2; ++sv) {
                    const int sc = w * 2 + sv;
                    const float* p = cb + (size_t)(cbase + (S + 1) * 16 + nl) * KDIM + (sc * 4 + g) * 8;
                    f32x4 a = *(const f32x4*)(p);
                    f32x4 bb = *(const f32x4*)(p + 4);
                    u16x8 uh, ul;
                    #pragma unroll
                    for (int jj = 0; jj < 4; ++jj) {
                        unsigned short h0 = f2bf(a[jj]);  uh[jj]   = h0; ul[jj]   = f2bf(a[jj] - bf2f(h0));
                        unsigned short h1 = f2bf(bb[jj]); uh[4+jj] = h1; ul[4+jj] = f2bf(bb[jj] - bf2f(h1));
                    }
                    rh[sv] = uh; rl[sv] = ul;
                }
            }
        }
        const f32x4 cn = *(const f32x4*)(cnorm + cbase + S * 16 + g * 4);
        {
            const char* buf = lds + b * PVBUF;
            f32x4 acc0 = {0.f, 0.f, 0.f, 0.f};
            f32x4 acc1 = {0.f, 0.f, 0.f, 0.f};
            #pragma unroll
            for (int s = 0; s < 8; ++s) {
                const int base = s * 1024 + lb;
                u16x8 ahi = *(const u16x8*)(buf + base);
                u16x8 alo = *(const u16x8*)(buf + 8192 + base);
                acc0 = mfma16(ahi, bhi[0][s],  acc0);
                acc0 = mfma16(ahi, bmid[0][s], acc0);
                acc0 = mfma16(alo, bhi[0][s],  acc0);
                acc1 = mfma16(ahi, bhi[1][s],  acc1);
                acc1 = mfma16(ahi, bmid[1][s], acc1);
                acc1 = mfma16(alo, bhi[1][s],  acc1);
            }
            #pragma unroll
            for (int r = 0; r < 4; ++r) {
                const int c = cbase + S * 16 + g * 4 + r;
                const float d0 = cn[r] - 2.0f * acc0[r];
                if (d0 < v1[0])      { v2[0] = v1[0]; i2[0] = i1[0]; v1[0] = d0; i1[0] = c; }
                else if (d0 < v2[0]) { v2[0] = d0; i2[0] = c; }
                const float d1 = cn[r] - 2.0f * acc1[r];
                if (d1 < v1[1])      { v2[1] = v1[1]; i2[1] = i1[1]; v1[1] = d1; i1[1] = c; }
                else if (d1 < v2[1]) { v2[1] = d1; i2[1] = c; }
            }
        }
        __syncthreads();   // PRE: drains DMA (back buffer ready) + read-sync
        if (!PRE) {
            if (S + 1 < PSTEP) {
                #pragma unroll
                for (int sv = 0; sv < 2; ++sv) {
                    const int sc = w * 2 + sv;
                    *(u16x8*)(nbuf + sc * 1024 + lb) = rh[sv];
                    *(u16x8*)(nbuf + 8192 + sc * 1024 + lb) = rl[sv];
                }
            }
            __syncthreads();
        }
    }

    // merge top-2 across the 4 g-lane-groups for each row-set
    #pragma unroll
    for (int rset = 0; rset < 2; ++rset) {
        #pragma unroll
        for (int off = 16; off <= 32; off <<= 1) {
            float ov1 = __shfl_xor(v1[rset], off); int oi1 = __shfl_xor(i1[rset], off);
            float ov2 = __shfl_xor(v2[rset], off); int oi2 = __shfl_xor(i2[rset], off);
            if (ov1 < v1[rset] || (ov1 == v1[rset] && oi1 < i1[rset])) {
                float tv = v1[rset]; int ti = i1[rset]; v1[rset] = ov1; i1[rset] = oi1; ov1 = tv; oi1 = ti;
                tv = v2[rset]; ti = i2[rset]; v2[rset] = ov2; i2[rset] = oi2; ov2 = tv; oi2 = ti;
            }
            if (ov1 < v2[rset] || (ov1 == v2[rset] && oi1 < i2[rset])) { v2[rset] = ov1; i2[rset] = oi1; }
        }
    }

    // write 8B index-pair record at [row][quar]
    if (g == 0) {
        #pragma unroll
        for (int rset = 0; rset < 2; ++rset) {
            i32x2 rec;
            rec[0] = i1[rset]; rec[1] = i2[rset];
            const size_t row = n0 + w * 32 + rset * 16 + nl;
            *(i32x2*)(recs + (row * 4 + quar) * 2) = rec;
        }
    }
}

// ====== vq merge: exact-refine ALL 8 candidates (4 quarters x top-2), gather, idx ===========
__global__ __launch_bounds__(256) void vq_merge_kernel(
    float* __restrict__ hbuf,
    const float* __restrict__ cb,
    const float* __restrict__ cnorm,
    const int* __restrict__ recs,
    float* __restrict__ idx_out)
{
    const int t  = threadIdx.x;
    const int w  = t >> 6;
    const int l  = t & 63;
    const int nl = l & 15;
    const int g  = l >> 4;
    const size_t n0 = (size_t)blockIdx.x * V_ROWS;
    const int row = w * 16 + nl;
    float* hrow = hbuf + (n0 + row) * KDIM;

    int cand[8];
    {
        const size_t rb = (n0 + row) * 8;
        #pragma unroll
        for (int q = 0; q < 4; ++q) {
            i32x2 rq = *(const i32x2*)(recs + rb + q * 2);
            int a = rq[0], b = rq[1];
            cand[2*q]   = (a < 0) ? 0 : (a > NCODES - 1 ? NCODES - 1 : a);
            cand[2*q+1] = (b < 0) ? 0 : (b > NCODES - 1 ? NCODES - 1 : b);
        }
    }

    f32x4 hreg[16];
    #pragma unroll
    for (int s = 0; s < 8; ++s) {
        hreg[2*s]   = *(const f32x4*)(hrow + s * 32 + g * 8);
        hreg[2*s+1] = *(const f32x4*)(hrow + s * 32 + g * 8 + 4);
    }

    float bestd = 3.4e38f;
    int   besti = 0x7fffffff;
    #pragma unroll
    for (int k = 0; k < 8; ++k) {
        const int ci = cand[k];
        const float* cp = cb + (size_t)ci * KDIM;
        float d = 0.f;
        #pragma unroll
        for (int s = 0; s < 8; ++s) {
            f32x4 a = *(const f32x4*)(cp + s * 32 + g * 8);
            f32x4 b = *(const f32x4*)(cp + s * 32 + g * 8 + 4);
            #pragma unroll
            for (int jj = 0; jj < 4; ++jj) {
                d = fmaf(a[jj], hreg[2*s][jj], d);
                d = fmaf(b[jj], hreg[2*s+1][jj], d);
            }
        }
        d += __shfl_xor(d, 16); d += __shfl_xor(d, 32);
        const float d2 = cnorm[ci] - 2.f * d;
        if (d2 < bestd || (d2 == bestd && ci < besti)) { bestd = d2; besti = ci; }
    }

    const float* cw = cb + (size_t)besti * KDIM;
    #pragma unroll
    for (int s = 0; s < 8; ++s) {
        *(f32x4*)(hrow + s * 32 + g * 8)     = *(const f32x4*)(cw + s * 32 + g * 8);
        *(f32x4*)(hrow + s * 32 + g * 8 + 4) = *(const f32x4*)(cw + s * 32 + g * 8 + 4);
    }
    if (g == 0) idx_out[n0 + row] = (float)besti;
}

// ---------------- r7-proven full-scan vq (fallback when ws too small for records) -----------
template<int PRE>
__global__ __launch_bounds__(256) void vq_kernel(
    float* __restrict__ hbuf,
    const float* __restrict__ cb,
    const float* __restrict__ cnorm,
    const unsigned short* __restrict__ cb_hi,
    const unsigned short* __restrict__ cb_lo,
    float* __restrict__ idx_out)
{
    __shared__ __align__(16) char lds[2 * VBUF];

    const int t  = threadIdx.x;
    const int w  = t >> 6;
    const int l  = t & 63;
    const int nl = l & 15;
    const int g  = l >> 4;
    const int lb = l * 16;
    const size_t n0 = (size_t)blockIdx.x * V_ROWS;
    const int row = w * 16 + nl;
    float* hrow = hbuf + (n0 + row) * KDIM;

    u16x8 bhi[8], bmid[8];
    #pragma unroll
    for (int s = 0; s < 8; ++s) {
        f32x4 a = *(const f32x4*)(hrow + s * 32 + g * 8);
        f32x4 b = *(const f32x4*)(hrow + s * 32 + g * 8 + 4);
        u16x8 uh, um;
        #pragma unroll
        for (int jj = 0; jj < 4; ++jj) {
            unsigned short h0 = f2bf(a[jj]); uh[jj]   = h0; um[jj]   = f2bf(a[jj] - bf2f(h0));
            unsigned short h1 = f2bf(b[jj]); uh[4+jj] = h1; um[4+jj] = f2bf(b[jj] - bf2f(h1));
        }
        bhi[s] = uh; bmid[s] = um;
    }

    float v1 = 3.4e38f, v2 = 3.4e38f;
    int   i1 = 0, i2 = 0;

    u16x8 rh[2][2], rl[2][2];

    #pragma unroll
    for (int t2 = 0; t2 < 2; ++t2)
        #pragma unroll
        for (int sv = 0; sv < 2; ++sv) {
            const int sst = w * 2 + sv;
            if (PRE) {
                const size_t off = (size_t)(t2 * 16 + nl) * KDIM + (sst * 4 + g) * 8;
                rh[t2][sv] = *(const u16x8*)(cb_hi + off);
                rl[t2][sv] = *(const u16x8*)(cb_lo + off);
            } else {
                const float* p = cb + (size_t)(t2 * 16 + nl) * KDIM + (sst * 4 + g) * 8;
                f32x4 a = *(const f32x4*)(p);
                f32x4 b = *(const f32x4*)(p + 4);
                u16x8 uh, ul;
                #pragma unroll
                for (int jj = 0; jj < 4; ++jj) {
                    unsigned short h0 = f2bf(a[jj]); uh[jj]   = h0; ul[jj]   = f2bf(a[jj] - bf2f(h0));
                    unsigned short h1 = f2bf(b[jj]); uh[4+jj] = h1; ul[4+jj] = f2bf(b[jj] - bf2f(h1));
                }
                rh[t2][sv] = uh; rl[t2][sv] = ul;
            }
        }
    #pragma unroll
    for (int t2 = 0; t2 < 2; ++t2)
        #pragma unroll
        for (int sv = 0; sv < 2; ++sv) {
            const int base = (t2 * 8 + w * 2 + sv) * 1024 + lb;
            *(u16x8*)(lds + base) = rh[t2][sv];
            *(u16x8*)(lds + 16384 + base) = rl[t2][sv];
        }
    __syncthreads();

    for (int S = 0; S < NSTEP; ++S) {
        const int b = S & 1;
        if (S + 1 < NSTEP) {
            #pragma unroll
            for (int t2 = 0; t2 < 2; ++t2)
                #pragma unroll
                for (int sv = 0; sv < 2; ++sv) {
                    const int sst = w * 2 + sv;
                    const int code = (S + 1) * 32 + t2 * 16 + nl;
                    if (PRE) {
                        const size_t off = (size_t)code * KDIM + (sst * 4 + g) * 8;
                        rh[t2][sv] = *(const u16x8*)(cb_hi + off);
                        rl[t2][sv] = *(const u16x8*)(cb_lo + off);
                    } else {
                        const float* p = cb + (size_t)code * KDIM + (sst * 4 + g) * 8;
                        f32x4 a = *(const f32x4*)(p);
                        f32x4 bb = *(const f32x4*)(p + 4);
                        u16x8 uh, ul;
                        #pragma unroll
                        for (int jj = 0; jj < 4; ++jj) {
                            unsigned short h0 = f2bf(a[jj]);  uh[jj]   = h0; ul[jj]   = f2bf(a[jj] - bf2f(h0));
                            unsigned short h1 = f2bf(bb[jj]); uh[4+jj] = h1; ul[4+jj] = f2bf(bb[jj] - bf2f(h1));
                        }
                        rh[t2][sv] = uh; rl[t2][sv] = ul;
                    }
                }
        }
        f32x4 cn0 = *(const f32x4*)(cnorm + S * 32 + g * 4);
        f32x4 cn1 = *(const f32x4*)(cnorm + S * 32 + 16 + g * 4);
        {
            const char* buf = lds + b * VBUF;
            #pragma unroll
            for (int t2 = 0; t2 < 2; ++t2) {
                f32x4 acc = {0.f, 0.f, 0.f, 0.f};
                #pragma unroll
                for (int s = 0; s < 8; ++s) {
                    const int base = (t2 * 8 + s) * 1024 + lb;
                    u16x8 ahi = *(const u16x8*)(buf + base);
                    u16x8 alo = *(const u16x8*)(buf + 16384 + base);
                    acc = mfma16(ahi, bhi[s],  acc);
                    acc = mfma16(ahi, bmid[s], acc);
                    acc = mfma16(alo, bhi[s],  acc);
                }
                const f32x4 cn = t2 ? cn1 : cn0;
                #pragma unroll
                for (int r = 0; r < 4; ++r) {
                    const float d2 = cn[r] - 2.0f * acc[r];
                    const int c = S * 32 + t2 * 16 + g * 4 + r;
                    if (d2 < v1)      { v2 = v1; i2 = i1; v1 = d2; i1 = c; }
                    else if (d2 < v2) { v2 = d2; i2 = c; }
                }
            }
        }
        __syncthreads();
        if (S + 1 < NSTEP) {
            char* nbuf = lds + (b ^ 1) * VBUF;
            #pragma unroll
            for (int t2 = 0; t2 < 2; ++t2)
                #pragma unroll
                for (int sv = 0; sv < 2; ++sv) {
                    const int base = (t2 * 8 + w * 2 + sv) * 1024 + lb;
                    *(u16x8*)(nbuf + base) = rh[t2][sv];
                    *(u16x8*)(nbuf + 16384 + base) = rl[t2][sv];
                }
        }
        __syncthreads();
    }

    #pragma unroll
    for (int off = 16; off <= 32; off <<= 1) {
        float ov1 = __shfl_xor(v1, off); int oi1 = __shfl_xor(i1, off);
        float ov2 = __shfl_xor(v2, off); int oi2 = __shfl_xor(i2, off);
        if (ov1 < v1 || (ov1 == v1 && oi1 < i1)) {
            float tv = v1; int ti = i1; v1 = ov1; i1 = oi1; ov1 = tv; oi1 = ti;
            tv = v2; ti = i2; v2 = ov2; i2 = oi2; ov2 = tv; oi2 = ti;
        }
        if (ov1 < v2 || (ov1 == v2 && oi1 < i2)) { v2 = ov1; i2 = oi1; }
    }

    i1 = (i1 < 0) ? 0 : (i1 > NCODES - 1 ? NCODES - 1 : i1);
    i2 = (i2 < 0) ? 0 : (i2 > NCODES - 1 ? NCODES - 1 : i2);

    const float* cp1 = cb + (size_t)i1 * KDIM;
    const float* cp2 = cb + (size_t)i2 * KDIM;
    float da = 0.f, db = 0.f;
    #pragma unroll
    for (int s = 0; s < 8; ++s) {
        f32x4 h0 = *(const f32x4*)(hrow + s * 32 + g * 8);
        f32x4 h1 = *(const f32x4*)(hrow + s * 32 + g * 8 + 4);
        f32x4 a1 = *(const f32x4*)(cp1 + s * 32 + g * 8);
        f32x4 b1 = *(const f32x4*)(cp1 + s * 32 + g * 8 + 4);
        f32x4 a2 = *(const f32x4*)(cp2 + s * 32 + g * 8);
        f32x4 b2 = *(const f32x4*)(cp2 + s * 32 + g * 8 + 4);
        #pragma unroll
        for (int jj = 0; jj < 4; ++jj) {
            da = fmaf(a1[jj], h0[jj], da); da = fmaf(b1[jj], h1[jj], da);
            db = fmaf(a2[jj], h0[jj], db); db = fmaf(b2[jj], h1[jj], db);
        }
    }
    da += __shfl_xor(da, 16); da += __shfl_xor(da, 32);
    db += __shfl_xor(db, 16); db += __shfl_xor(db, 32);
    const float d2a = cnorm[i1] - 2.f * da;
    const float d2b = cnorm[i2] - 2.f * db;
    const int win = (d2a < d2b || (d2a == d2b && i1 < i2)) ? i1 : i2;

    const float* cw = cb + (size_t)win * KDIM;
    #pragma unroll
    for (int s = 0; s < 8; ++s) {
        *(f32x4*)(hrow + s * 32 + g * 8)     = *(const f32x4*)(cw + s * 32 + g * 8);
        *(f32x4*)(hrow + s * 32 + g * 8 + 4) = *(const f32x4*)(cw + s * 32 + g * 8 + 4);
    }
    if (g == 0) idx_out[n0 + row] = (float)win;
}

extern "C" void kernel_launch(void* const* d_in, const int* in_sizes, int n_in,
                              void* d_out, int out_size, void* d_ws, size_t ws_size,
                              hipStream_t stream) {
    (void)in_sizes; (void)n_in; (void)out_size;
    const float* x    = (const float*)d_in[0];
    const float* W    = (const float*)d_in[1];
    const float* bvec = (const float*)d_in[2];
    const float* cb   = (const float*)d_in[3];

    float* codes_out = (float*)d_out;                       // doubles as h buffer
    float* idx_out   = (float*)d_out + (size_t)NROWS * KDIM;

    // ws layout: cnorm[16KB] | recs[512KB, int] | cb_hi[2MB] | cb_lo[2MB] | wt[3x0.5MB]
    float* cnorm = (float*)d_ws;
    int*   recs  = (int*)((char*)d_ws + 16384);
    unsigned short* cb_hi = (unsigned short*)((char*)d_ws + 16384 + 524288);
    unsigned short* cb_lo = cb_hi + (size_t)NCODES * KDIM;
    unsigned short* wt_hi = cb_lo + (size_t)NCODES * KDIM;
    unsigned short* wt_md = wt_hi + (size_t)INDIM * KDIM;
    unsigned short* wt_lo = wt_md + (size_t)INDIM * KDIM;

    const size_t need_rec  = 16384 + 524288;
    const size_t need_cb   = need_rec + (size_t)NCODES * KDIM * 2 * sizeof(unsigned short);
    const size_t need_full = need_cb + (size_t)INDIM * KDIM * 3 * sizeof(unsigned short);

    const int use_split = (ws_size >= need_rec) ? 1 : 0;
    const int pre_cb    = (ws_size >= need_cb) ? 1 : 0;
    const int fast_g    = (ws_size >= need_full) ? 1 : 0;

    if (fast_g) {
        wprep_kernel<<<INDIM / 4, 256, 0, stream>>>(W, wt_hi, wt_md, wt_lo);
        gemm_mfma_kernel<<<NROWS / MG_ROWS, 256, 0, stream>>>(x, wt_hi, wt_md, wt_lo, bvec, codes_out);
    } else {
        gemm_fb_kernel<<<NROWS / G_ROWS, 256, 0, stream>>>(x, W, bvec, codes_out);
    }
    prep_kernel<<<NCODES / 4, 256, 0, stream>>>(cb, cnorm, cb_hi, cb_lo, pre_cb);

    if (use_split) {
        if (pre_cb)
            vq_partial_kernel<1><<<(NROWS / P_ROWS) * 4, 256, 0, stream>>>(codes_out, cb, cnorm, cb_hi, cb_lo, recs);
        else
            vq_partial_kernel<0><<<(NROWS / P_ROWS) * 4, 256, 0, stream>>>(codes_out, cb, cnorm, cb_hi, cb_lo, recs);
        vq_merge_kernel<<<NROWS / V_ROWS, 256, 0, stream>>>(codes_out, cb, cnorm, recs, idx_out);
    } else {
        if (pre_cb)
            vq_kernel<1><<<NROWS / V_ROWS, 256, 0, stream>>>(codes_out, cb, cnorm, cb_hi, cb_lo, idx_out);
        else
            vq_kernel<0><<<NROWS / V_ROWS, 256, 0, stream>>>(codes_out, cb, cnorm, cb_hi, cb_lo, idx_out);
    }
}

// Round 16
// 307.314 us; speedup vs baseline: 1.5876x; 1.5876x over previous
//
#include <hip/hip_runtime.h>

#define NROWS   16384
#define INDIM   1024
#define KDIM    256
#define NCODES  4096
#define G_ROWS  32       // rows per fallback-gemm block
#define V_ROWS  64       // rows per fallback vq / merge block
#define P_ROWS  128      // rows per vq_partial block
#define PSTEP   64       // vq_partial: steps of 16 codes (quarter = 1024 codes)
#define NSTEP   128      // full-scan vq fallback: steps of 32 codes

// vq_partial LDS: 2 buffers x (hi 8KB + lo 8KB) = 32 KB
#define PVBUF   16384
// fallback vq LDS: 2 buffers x (hi 16KB + lo 16KB)
#define VBUF    32768

// gemm LDS: X 3x8KB ([s][rs][lane]) + W 3x32KB ([s][cidx][lane])
#define MG_ROWS 64
#define MG_KC   64
#define MG_NCH  (INDIM / MG_KC)   // 16
#define XP(p)   ((p) * 8192)
#define WP(p)   (24576 + (p) * 32768)
#define MG_LDS  122880

typedef float f32x4 __attribute__((ext_vector_type(4)));
typedef int   i32x2 __attribute__((ext_vector_type(2)));
typedef short short8 __attribute__((ext_vector_type(8)));
typedef unsigned short u16x8 __attribute__((ext_vector_type(8)));
typedef unsigned short u16x4 __attribute__((ext_vector_type(4)));

__device__ inline unsigned short f2bf(float f) {
    unsigned u = __builtin_bit_cast(unsigned, f);
    u = (u + 0x7fffu + ((u >> 16) & 1u)) >> 16;
    return (unsigned short)u;
}
__device__ inline float bf2f(unsigned short h) {
    unsigned u = ((unsigned)h) << 16;
    return __builtin_bit_cast(float, u);
}
__device__ inline f32x4 mfma16(u16x8 a, u16x8 b, f32x4 c) {
    return __builtin_amdgcn_mfma_f32_16x16x32_bf16(
        __builtin_bit_cast(short8, a), __builtin_bit_cast(short8, b), c, 0, 0, 0);
}

// async global->LDS DMA, 16B/lane; dest = wave-uniform base + lane*16 (HW-implicit)
__device__ inline void gload16(const void* g, void* l) {
    __builtin_amdgcn_global_load_lds(
        (const __attribute__((address_space(1))) unsigned int*)g,
        (__attribute__((address_space(3))) unsigned int*)l,
        16, 0, 0);
}

// ---------------- prep: W[1024][256] f32 -> W_T 3-way bf16 split [256][1024] ----------------
__global__ __launch_bounds__(256) void wprep_kernel(const float* __restrict__ W,
                                                    unsigned short* __restrict__ wt_hi,
                                                    unsigned short* __restrict__ wt_md,
                                                    unsigned short* __restrict__ wt_lo) {
    const int t = threadIdx.x;
    const int k = blockIdx.x * 4 + (t >> 6);
    const int c0 = (t & 63) * 4;
    f32x4 v = *(const f32x4*)(W + (size_t)k * KDIM + c0);
    #pragma unroll
    for (int i = 0; i < 4; ++i) {
        const unsigned short h = f2bf(v[i]);
        const float r1 = v[i] - bf2f(h);
        const unsigned short m = f2bf(r1);
        const unsigned short lo = f2bf(r1 - bf2f(m));
        wt_hi[(size_t)(c0 + i) * INDIM + k] = h;
        wt_md[(size_t)(c0 + i) * INDIM + k] = m;
        wt_lo[(size_t)(c0 + i) * INDIM + k] = lo;
    }
}

// ---------------- MFMA gemm: h = x@W + b (6-pass 3-way split, f32-class accuracy) ----------------
__global__ __launch_bounds__(256, 1) void gemm_mfma_kernel(const float* __restrict__ x,
                                                           const unsigned short* __restrict__ wt_hi,
                                                           const unsigned short* __restrict__ wt_md,
                                                           const unsigned short* __restrict__ wt_lo,
                                                           const float* __restrict__ bvec,
                                                           float* __restrict__ hbuf) {
    __shared__ __align__(16) char lds[MG_LDS];

    const int t  = threadIdx.x;
    const int w  = t >> 6;
    const int l  = t & 63;
    const int nl = l & 15;
    const int g  = l >> 4;
    const size_t n0 = (size_t)blockIdx.x * MG_ROWS;
    const int lb = l * 16;

    f32x4 acc[4][4];
    #pragma unroll
    for (int a = 0; a < 4; ++a)
        #pragma unroll
        for (int b = 0; b < 4; ++b) acc[a][b] = (f32x4){0.f, 0.f, 0.f, 0.f};

    for (int kc = 0; kc < MG_NCH; ++kc) {
        f32x4 xa[2], xb[2];
        #pragma unroll
        for (int c = 0; c < 2; ++c) {
            const int idx = w * 2 + c;
            const int sX = idx >> 2, rsX = idx & 3;
            const float* p = x + (n0 + rsX * 16 + nl) * INDIM + kc * MG_KC + sX * 32 + g * 8;
            xa[c] = *(const f32x4*)(p);
            xb[c] = *(const f32x4*)(p + 4);
        }
        u16x8 wh[8], wm[8], wl[8];
        #pragma unroll
        for (int ci = 0; ci < 4; ++ci)
            #pragma unroll
            for (int sW = 0; sW < 2; ++sW) {
                const int q = ci * 2 + sW;
                const size_t off = (size_t)((w * 4 + ci) * 16 + nl) * INDIM
                                 + kc * MG_KC + sW * 32 + g * 8;
                wh[q] = *(const u16x8*)(wt_hi + off);
                wm[q] = *(const u16x8*)(wt_md + off);
                wl[q] = *(const u16x8*)(wt_lo + off);
            }
        __syncthreads();

        #pragma unroll
        for (int c = 0; c < 2; ++c) {
            const int idx = w * 2 + c;
            const int sX = idx >> 2, rsX = idx & 3;
            u16x8 xh, xm, xl;
            #pragma unroll
            for (int e = 0; e < 4; ++e) {
                const float a0 = xa[c][e], a1 = xb[c][e];
                const unsigned short h0 = f2bf(a0);
                const float r10 = a0 - bf2f(h0);
                const unsigned short m0 = f2bf(r10);
                const unsigned short l0 = f2bf(r10 - bf2f(m0));
                const unsigned short h1 = f2bf(a1);
                const float r11 = a1 - bf2f(h1);
                const unsigned short m1 = f2bf(r11);
                const unsigned short l1 = f2bf(r11 - bf2f(m1));
                xh[e] = h0; xh[4+e] = h1;
                xm[e] = m0; xm[4+e] = m1;
                xl[e] = l0; xl[4+e] = l1;
            }
            const int base = (sX * 4 + rsX) * 1024 + lb;
            *(u16x8*)(lds + XP(0) + base) = xh;
            *(u16x8*)(lds + XP(1) + base) = xm;
            *(u16x8*)(lds + XP(2) + base) = xl;
        }
        #pragma unroll
        for (int ci = 0; ci < 4; ++ci)
            #pragma unroll
            for (int sW = 0; sW < 2; ++sW) {
                const int q = ci * 2 + sW;
                const int base = (sW * 16 + w * 4 + ci) * 1024 + lb;
                *(u16x8*)(lds + WP(0) + base) = wh[q];
                *(u16x8*)(lds + WP(1) + base) = wm[q];
                *(u16x8*)(lds + WP(2) + base) = wl[q];
            }
        __syncthreads();

        #pragma unroll
        for (int s = 0; s < 2; ++s) {
            u16x8 bh[4], bm[4], bl[4], ah[4], am[4], al[4];
            #pragma unroll
            for (int rs = 0; rs < 4; ++rs) {
                const int base = (s * 4 + rs) * 1024 + lb;
                bh[rs] = *(const u16x8*)(lds + XP(0) + base);
                bm[rs] = *(const u16x8*)(lds + XP(1) + base);
                bl[rs] = *(const u16x8*)(lds + XP(2) + base);
            }
            #pragma unroll
            for (int ct = 0; ct < 4; ++ct) {
                const int base = (s * 16 + w * 4 + ct) * 1024 + lb;
                ah[ct] = *(const u16x8*)(lds + WP(0) + base);
                am[ct] = *(const u16x8*)(lds + WP(1) + base);
                al[ct] = *(const u16x8*)(lds + WP(2) + base);
            }
            #pragma unroll
            for (int ct = 0; ct < 4; ++ct)
                #pragma unroll
                for (int rs = 0; rs < 4; ++rs) {
                    acc[ct][rs] = mfma16(ah[ct], bh[rs], acc[ct][rs]);
                    acc[ct][rs] = mfma16(ah[ct], bm[rs], acc[ct][rs]);
                    acc[ct][rs] = mfma16(am[ct], bh[rs], acc[ct][rs]);
                    acc[ct][rs] = mfma16(ah[ct], bl[rs], acc[ct][rs]);
                    acc[ct][rs] = mfma16(al[ct], bh[rs], acc[ct][rs]);
                    acc[ct][rs] = mfma16(am[ct], bm[rs], acc[ct][rs]);
                }
        }
    }

    #pragma unroll
    for (int ct = 0; ct < 4; ++ct) {
        float bv[4];
        #pragma unroll
        for (int r = 0; r < 4; ++r) bv[r] = bvec[w * 64 + ct * 16 + g * 4 + r];
        #pragma unroll
        for (int rs = 0; rs < 4; ++rs) {
            const size_t row = n0 + rs * 16 + nl;
            #pragma unroll
            for (int r = 0; r < 4; ++r)
                hbuf[row * KDIM + w * 64 + ct * 16 + g * 4 + r] = acc[ct][rs][r] + bv[r];
        }
    }
}

// ---------------- fallback f32 gemm ----------------
__global__ __launch_bounds__(256, 2) void gemm_fb_kernel(const float* __restrict__ x,
                                                         const float* __restrict__ W,
                                                         const float* __restrict__ bvec,
                                                         float* __restrict__ hbuf) {
    const int t  = threadIdx.x;
    const int cg = t & 15;
    const int rg = t >> 4;
    const size_t n0 = (size_t)blockIdx.x * G_ROWS;
    const int c0 = cg * 16;

    float acc[2][16];
    #pragma unroll
    for (int j = 0; j < 2; ++j)
        #pragma unroll
        for (int cc = 0; cc < 16; ++cc) acc[j][cc] = 0.f;

    for (int k4 = 0; k4 < INDIM / 4; ++k4) {
        const int k = k4 * 4;
        f32x4 xv[2];
        #pragma unroll
        for (int j = 0; j < 2; ++j)
            xv[j] = *(const f32x4*)(x + (n0 + rg + 16 * j) * INDIM + k);
        f32x4 wv[4][4];
        #pragma unroll
        for (int kk = 0; kk < 4; ++kk)
            #pragma unroll
            for (int q = 0; q < 4; ++q)
                wv[kk][q] = *(const f32x4*)(W + (size_t)(k + kk) * KDIM + c0 + 4 * q);
        #pragma unroll
        for (int j = 0; j < 2; ++j)
            #pragma unroll
            for (int kk = 0; kk < 4; ++kk) {
                const float xs = xv[j][kk];
                #pragma unroll
                for (int q = 0; q < 4; ++q)
                    #pragma unroll
                    for (int e = 0; e < 4; ++e)
                        acc[j][4*q+e] = fmaf(xs, wv[kk][q][e], acc[j][4*q+e]);
            }
    }
    #pragma unroll
    for (int j = 0; j < 2; ++j) {
        float* dst = hbuf + (n0 + rg + 16 * j) * KDIM + c0;
        #pragma unroll
        for (int q = 0; q < 4; ++q) {
            f32x4 v;
            #pragma unroll
            for (int e = 0; e < 4; ++e) v[e] = acc[j][4*q+e] + bvec[c0 + 4*q + e];
            *(f32x4*)(dst + 4*q) = v;
        }
    }
}

// ---------------- prep: cnorm + optional bf16 hi/lo split of cb ----------------
__global__ __launch_bounds__(256) void prep_kernel(const float* __restrict__ cb,
                                                   float* __restrict__ cnorm,
                                                   unsigned short* __restrict__ cb_hi,
                                                   unsigned short* __restrict__ cb_lo,
                                                   int do_split) {
    const int c    = blockIdx.x * 4 + (threadIdx.x >> 6);
    const int lane = threadIdx.x & 63;
    f32x4 v = ((const f32x4*)(cb + (size_t)c * KDIM))[lane];
    if (do_split) {
        u16x4 h4, l4;
        #pragma unroll
        for (int j = 0; j < 4; ++j) {
            unsigned short h = f2bf(v[j]);
            h4[j] = h;
            l4[j] = f2bf(v[j] - bf2f(h));
        }
        *(u16x4*)(cb_hi + (size_t)c * KDIM + lane * 4) = h4;
        *(u16x4*)(cb_lo + (size_t)c * KDIM + lane * 4) = l4;
    }
    float s = v[0]*v[0] + v[1]*v[1] + v[2]*v[2] + v[3]*v[3];
    #pragma unroll
    for (int off = 1; off < 64; off <<= 1) s += __shfl_xor(s, off);
    if (lane == 0) cnorm[c] = s;
}

// ===== vq partial: 128 rows/block, quarter of codes, 16 codes/step, no-spill bounds =========
template<int PRE>
__global__ __launch_bounds__(256, 3) void vq_partial_kernel(
    const float* __restrict__ hbuf,
    const float* __restrict__ cb,
    const float* __restrict__ cnorm,
    const unsigned short* __restrict__ cb_hi,
    const unsigned short* __restrict__ cb_lo,
    int* __restrict__ recs)                    // [NROWS][4] int2 {i1,i2}
{
    __shared__ __align__(16) char lds[2 * PVBUF];   // 32 KB

    const int t  = threadIdx.x;
    const int w  = t >> 6;
    const int l  = t & 63;
    const int nl = l & 15;
    const int g  = l >> 4;
    const int lb = l * 16;
    const int bid  = blockIdx.x;
    const int quar = bid & 3;
    const int cbase = quar * 1024;
    const size_t n0 = (size_t)(bid >> 2) * P_ROWS;

    // B-fragments for 2 row-sets: rows w*32 + rset*16 + nl
    u16x8 bhi[2][8], bmid[2][8];
    #pragma unroll
    for (int rset = 0; rset < 2; ++rset) {
        const float* hrow = hbuf + (n0 + w * 32 + rset * 16 + nl) * KDIM;
        #pragma unroll
        for (int s = 0; s < 8; ++s) {
            f32x4 a = *(const f32x4*)(hrow + s * 32 + g * 8);
            f32x4 b = *(const f32x4*)(hrow + s * 32 + g * 8 + 4);
            u16x8 uh, um;
            #pragma unroll
            for (int jj = 0; jj < 4; ++jj) {
                unsigned short h0 = f2bf(a[jj]); uh[jj]   = h0; um[jj]   = f2bf(a[jj] - bf2f(h0));
                unsigned short h1 = f2bf(b[jj]); uh[4+jj] = h1; um[4+jj] = f2bf(b[jj] - bf2f(h1));
            }
            bhi[rset][s] = uh; bmid[rset][s] = um;
        }
    }

    float v1[2] = {3.4e38f, 3.4e38f}, v2[2] = {3.4e38f, 3.4e38f};
    int   i1[2] = {0, 0},            i2[2] = {0, 0};

    u16x8 rh[2], rl[2];   // non-PRE only

    // ---- prologue: stage step 0 into buffer 0; wave w covers chunks sc = w*2, w*2+1 ----
    if (PRE) {
        #pragma unroll
        for (int sv = 0; sv < 2; ++sv) {
            const int sc = w * 2 + sv;
            const size_t off = (size_t)(cbase + nl) * KDIM + (sc * 4 + g) * 8;
            gload16(cb_hi + off, lds + sc * 1024);
            gload16(cb_lo + off, lds + 8192 + sc * 1024);
        }
    } else {
        #pragma unroll
        for (int sv = 0; sv < 2; ++sv) {
            const int sc = w * 2 + sv;
            const float* p = cb + (size_t)(cbase + nl) * KDIM + (sc * 4 + g) * 8;
            f32x4 a = *(const f32x4*)(p);
            f32x4 b = *(const f32x4*)(p + 4);
            u16x8 uh, ul;
            #pragma unroll
            for (int jj = 0; jj < 4; ++jj) {
                unsigned short h0 = f2bf(a[jj]); uh[jj]   = h0; ul[jj]   = f2bf(a[jj] - bf2f(h0));
                unsigned short h1 = f2bf(b[jj]); uh[4+jj] = h1; ul[4+jj] = f2bf(b[jj] - bf2f(h1));
            }
            rh[sv] = uh; rl[sv] = ul;
        }
        #pragma unroll
        for (int sv = 0; sv < 2; ++sv) {
            const int sc = w * 2 + sv;
            *(u16x8*)(lds + sc * 1024 + lb) = rh[sv];
            *(u16x8*)(lds + 8192 + sc * 1024 + lb) = rl[sv];
        }
    }
    __syncthreads();

    for (int S = 0; S < PSTEP; ++S) {
        const int b = S & 1;
        char* nbuf = lds + (b ^ 1) * PVBUF;
        if (S + 1 < PSTEP) {
            if (PRE) {
                #pragma unroll
                for (int sv = 0; sv < 2; ++sv) {
                    const int sc = w * 2 + sv;
                    const size_t off = (size_t)(cbase + (S + 1) * 16 + nl) * KDIM + (sc * 4 + g) * 8;
                    gload16(cb_hi + off, nbuf + sc * 1024);
                    gload16(cb_lo + off, nbuf + 8192 + sc * 1024);
                }
            } else {
                #pragma unroll
                for (int sv = 0; sv < 2; ++sv) {
                    const int sc = w * 2 + sv;
                    const float* p = cb + (size_t)(cbase + (S + 1) * 16 + nl) * KDIM + (sc * 4 + g) * 8;
                    f32x4 a = *(const f32x4*)(p);
                    f32x4 bb = *(const f32x4*)(p + 4);
                    u16x8 uh, ul;
                    #pragma unroll
                    for (int jj = 0; jj < 4; ++jj) {
                        unsigned short h0 = f2bf(a[jj]);  uh[jj]   = h0; ul[jj]   = f2bf(a[jj] - bf2f(h0));
                        unsigned short h1 = f2bf(bb[jj]); uh[4+jj] = h1; ul[4+jj] = f2bf(bb[jj] - bf2f(h1));
                    }
                    rh[sv] = uh; rl[sv] = ul;
                }
            }
        }
        const f32x4 cn = *(const f32x4*)(cnorm + cbase + S * 16 + g * 4);
        {
            const char* buf = lds + b * PVBUF;
            f32x4 acc0 = {0.f, 0.f, 0.f, 0.f};
            f32x4 acc1 = {0.f, 0.f, 0.f, 0.f};
            #pragma unroll
            for (int s = 0; s < 8; ++s) {
                const int base = s * 1024 + lb;
                u16x8 ahi = *(const u16x8*)(buf + base);
                u16x8 alo = *(const u16x8*)(buf + 8192 + base);
                acc0 = mfma16(ahi, bhi[0][s],  acc0);
                acc0 = mfma16(ahi, bmid[0][s], acc0);
                acc0 = mfma16(alo, bhi[0][s],  acc0);
                acc1 = mfma16(ahi, bhi[1][s],  acc1);
                acc1 = mfma16(ahi, bmid[1][s], acc1);
                acc1 = mfma16(alo, bhi[1][s],  acc1);
            }
            #pragma unroll
            for (int r = 0; r < 4; ++r) {
                const int c = cbase + S * 16 + g * 4 + r;
                const float d0 = cn[r] - 2.0f * acc0[r];
                if (d0 < v1[0])      { v2[0] = v1[0]; i2[0] = i1[0]; v1[0] = d0; i1[0] = c; }
                else if (d0 < v2[0]) { v2[0] = d0; i2[0] = c; }
                const float d1 = cn[r] - 2.0f * acc1[r];
                if (d1 < v1[1])      { v2[1] = v1[1]; i2[1] = i1[1]; v1[1] = d1; i1[1] = c; }
                else if (d1 < v2[1]) { v2[1] = d1; i2[1] = c; }
            }
        }
        __syncthreads();   // PRE: drains DMA (back buffer ready) + read-sync
        if (!PRE) {
            if (S + 1 < PSTEP) {
                #pragma unroll
                for (int sv = 0; sv < 2; ++sv) {
                    const int sc = w * 2 + sv;
                    *(u16x8*)(nbuf + sc * 1024 + lb) = rh[sv];
                    *(u16x8*)(nbuf + 8192 + sc * 1024 + lb) = rl[sv];
                }
            }
            __syncthreads();
        }
    }

    // merge top-2 across the 4 g-lane-groups for each row-set
    #pragma unroll
    for (int rset = 0; rset < 2; ++rset) {
        #pragma unroll
        for (int off = 16; off <= 32; off <<= 1) {
            float ov1 = __shfl_xor(v1[rset], off); int oi1 = __shfl_xor(i1[rset], off);
            float ov2 = __shfl_xor(v2[rset], off); int oi2 = __shfl_xor(i2[rset], off);
            if (ov1 < v1[rset] || (ov1 == v1[rset] && oi1 < i1[rset])) {
                float tv = v1[rset]; int ti = i1[rset]; v1[rset] = ov1; i1[rset] = oi1; ov1 = tv; oi1 = ti;
                tv = v2[rset]; ti = i2[rset]; v2[rset] = ov2; i2[rset] = oi2; ov2 = tv; oi2 = ti;
            }
            if (ov1 < v2[rset] || (ov1 == v2[rset] && oi1 < i2[rset])) { v2[rset] = ov1; i2[rset] = oi1; }
        }
    }

    // write 8B index-pair record at [row][quar]
    if (g == 0) {
        #pragma unroll
        for (int rset = 0; rset < 2; ++rset) {
            i32x2 rec;
            rec[0] = i1[rset]; rec[1] = i2[rset];
            const size_t row = n0 + w * 32 + rset * 16 + nl;
            *(i32x2*)(recs + (row * 4 + quar) * 2) = rec;
        }
    }
}

// ====== vq merge: exact-refine ALL 8 candidates (4 quarters x top-2), gather, idx ===========
__global__ __launch_bounds__(256) void vq_merge_kernel(
    float* __restrict__ hbuf,
    const float* __restrict__ cb,
    const float* __restrict__ cnorm,
    const int* __restrict__ recs,
    float* __restrict__ idx_out)
{
    const int t  = threadIdx.x;
    const int w  = t >> 6;
    const int l  = t & 63;
    const int nl = l & 15;
    const int g  = l >> 4;
    const size_t n0 = (size_t)blockIdx.x * V_ROWS;
    const int row = w * 16 + nl;
    float* hrow = hbuf + (n0 + row) * KDIM;

    int cand[8];
    {
        const size_t rb = (n0 + row) * 8;
        #pragma unroll
        for (int q = 0; q < 4; ++q) {
            i32x2 rq = *(const i32x2*)(recs + rb + q * 2);
            int a = rq[0], b = rq[1];
            cand[2*q]   = (a < 0) ? 0 : (a > NCODES - 1 ? NCODES - 1 : a);
            cand[2*q+1] = (b < 0) ? 0 : (b > NCODES - 1 ? NCODES - 1 : b);
        }
    }

    f32x4 hreg[16];
    #pragma unroll
    for (int s = 0; s < 8; ++s) {
        hreg[2*s]   = *(const f32x4*)(hrow + s * 32 + g * 8);
        hreg[2*s+1] = *(const f32x4*)(hrow + s * 32 + g * 8 + 4);
    }

    float bestd = 3.4e38f;
    int   besti = 0x7fffffff;
    #pragma unroll
    for (int k = 0; k < 8; ++k) {
        const int ci = cand[k];
        const float* cp = cb + (size_t)ci * KDIM;
        float d = 0.f;
        #pragma unroll
        for (int s = 0; s < 8; ++s) {
            f32x4 a = *(const f32x4*)(cp + s * 32 + g * 8);
            f32x4 b = *(const f32x4*)(cp + s * 32 + g * 8 + 4);
            #pragma unroll
            for (int jj = 0; jj < 4; ++jj) {
                d = fmaf(a[jj], hreg[2*s][jj], d);
                d = fmaf(b[jj], hreg[2*s+1][jj], d);
            }
        }
        d += __shfl_xor(d, 16); d += __shfl_xor(d, 32);
        const float d2 = cnorm[ci] - 2.f * d;
        if (d2 < bestd || (d2 == bestd && ci < besti)) { bestd = d2; besti = ci; }
    }

    const float* cw = cb + (size_t)besti * KDIM;
    #pragma unroll
    for (int s = 0; s < 8; ++s) {
        *(f32x4*)(hrow + s * 32 + g * 8)     = *(const f32x4*)(cw + s * 32 + g * 8);
        *(f32x4*)(hrow + s * 32 + g * 8 + 4) = *(const f32x4*)(cw + s * 32 + g * 8 + 4);
    }
    if (g == 0) idx_out[n0 + row] = (float)besti;
}

// ---------------- r7-proven full-scan vq (fallback when ws too small for records) -----------
template<int PRE>
__global__ __launch_bounds__(256) void vq_kernel(
    float* __restrict__ hbuf,
    const float* __restrict__ cb,
    const float* __restrict__ cnorm,
    const unsigned short* __restrict__ cb_hi,
    const unsigned short* __restrict__ cb_lo,
    float* __restrict__ idx_out)
{
    __shared__ __align__(16) char lds[2 * VBUF];

    const int t  = threadIdx.x;
    const int w  = t >> 6;
    const int l  = t & 63;
    const int nl = l & 15;
    const int g  = l >> 4;
    const int lb = l * 16;
    const size_t n0 = (size_t)blockIdx.x * V_ROWS;
    const int row = w * 16 + nl;
    float* hrow = hbuf + (n0 + row) * KDIM;

    u16x8 bhi[8], bmid[8];
    #pragma unroll
    for (int s = 0; s < 8; ++s) {
        f32x4 a = *(const f32x4*)(hrow + s * 32 + g * 8);
        f32x4 b = *(const f32x4*)(hrow + s * 32 + g * 8 + 4);
        u16x8 uh, um;
        #pragma unroll
        for (int jj = 0; jj < 4; ++jj) {
            unsigned short h0 = f2bf(a[jj]); uh[jj]   = h0; um[jj]   = f2bf(a[jj] - bf2f(h0));
            unsigned short h1 = f2bf(b[jj]); uh[4+jj] = h1; um[4+jj] = f2bf(b[jj] - bf2f(h1));
        }
        bhi[s] = uh; bmid[s] = um;
    }

    float v1 = 3.4e38f, v2 = 3.4e38f;
    int   i1 = 0, i2 = 0;

    u16x8 rh[2][2], rl[2][2];

    #pragma unroll
    for (int t2 = 0; t2 < 2; ++t2)
        #pragma unroll
        for (int sv = 0; sv < 2; ++sv) {
            const int sst = w * 2 + sv;
            if (PRE) {
                const size_t off = (size_t)(t2 * 16 + nl) * KDIM + (sst * 4 + g) * 8;
                rh[t2][sv] = *(const u16x8*)(cb_hi + off);
                rl[t2][sv] = *(const u16x8*)(cb_lo + off);
            } else {
                const float* p = cb + (size_t)(t2 * 16 + nl) * KDIM + (sst * 4 + g) * 8;
                f32x4 a = *(const f32x4*)(p);
                f32x4 b = *(const f32x4*)(p + 4);
                u16x8 uh, ul;
                #pragma unroll
                for (int jj = 0; jj < 4; ++jj) {
                    unsigned short h0 = f2bf(a[jj]); uh[jj]   = h0; ul[jj]   = f2bf(a[jj] - bf2f(h0));
                    unsigned short h1 = f2bf(b[jj]); uh[4+jj] = h1; ul[4+jj] = f2bf(b[jj] - bf2f(h1));
                }
                rh[t2][sv] = uh; rl[t2][sv] = ul;
            }
        }
    #pragma unroll
    for (int t2 = 0; t2 < 2; ++t2)
        #pragma unroll
        for (int sv = 0; sv < 2; ++sv) {
            const int base = (t2 * 8 + w * 2 + sv) * 1024 + lb;
            *(u16x8*)(lds + base) = rh[t2][sv];
            *(u16x8*)(lds + 16384 + base) = rl[t2][sv];
        }
    __syncthreads();

    for (int S = 0; S < NSTEP; ++S) {
        const int b = S & 1;
        if (S + 1 < NSTEP) {
            #pragma unroll
            for (int t2 = 0; t2 < 2; ++t2)
                #pragma unroll
                for (int sv = 0; sv < 2; ++sv) {
                    const int sst = w * 2 + sv;
                    const int code = (S + 1) * 32 + t2 * 16 + nl;
                    if (PRE) {
                        const size_t off = (size_t)code * KDIM + (sst * 4 + g) * 8;
                        rh[t2][sv] = *(const u16x8*)(cb_hi + off);
                        rl[t2][sv] = *(const u16x8*)(cb_lo + off);
                    } else {
                        const float* p = cb + (size_t)code * KDIM + (sst * 4 + g) * 8;
                        f32x4 a = *(const f32x4*)(p);
                        f32x4 bb = *(const f32x4*)(p + 4);
                        u16x8 uh, ul;
                        #pragma unroll
                        for (int jj = 0; jj < 4; ++jj) {
                            unsigned short h0 = f2bf(a[jj]);  uh[jj]   = h0; ul[jj]   = f2bf(a[jj] - bf2f(h0));
                            unsigned short h1 = f2bf(bb[jj]); uh[4+jj] = h1; ul[4+jj] = f2bf(bb[jj] - bf2f(h1));
                        }
                        rh[t2][sv] = uh; rl[t2][sv] = ul;
                    }
                }
        }
        f32x4 cn0 = *(const f32x4*)(cnorm + S * 32 + g * 4);
        f32x4 cn1 = *(const f32x4*)(cnorm + S * 32 + 16 + g * 4);
        {
            const char* buf = lds + b * VBUF;
            #pragma unroll
            for (int t2 = 0; t2 < 2; ++t2) {
                f32x4 acc = {0.f, 0.f, 0.f, 0.f};
                #pragma unroll
                for (int s = 0; s < 8; ++s) {
                    const int base = (t2 * 8 + s) * 1024 + lb;
                    u16x8 ahi = *(const u16x8*)(buf + base);
                    u16x8 alo = *(const u16x8*)(buf + 16384 + base);
                    acc = mfma16(ahi, bhi[s],  acc);
                    acc = mfma16(ahi, bmid[s], acc);
                    acc = mfma16(alo, bhi[s],  acc);
                }
                const f32x4 cn = t2 ? cn1 : cn0;
                #pragma unroll
                for (int r = 0; r < 4; ++r) {
                    const float d2 = cn[r] - 2.0f * acc[r];
                    const int c = S * 32 + t2 * 16 + g * 4 + r;
                    if (d2 < v1)      { v2 = v1; i2 = i1; v1 = d2; i1 = c; }
                    else if (d2 < v2) { v2 = d2; i2 = c; }
                }
            }
        }
        __syncthreads();
        if (S + 1 < NSTEP) {
            char* nbuf = lds + (b ^ 1) * VBUF;
            #pragma unroll
            for (int t2 = 0; t2 < 2; ++t2)
                #pragma unroll
                for (int sv = 0; sv < 2; ++sv) {
                    const int base = (t2 * 8 + w * 2 + sv) * 1024 + lb;
                    *(u16x8*)(nbuf + base) = rh[t2][sv];
                    *(u16x8*)(nbuf + 16384 + base) = rl[t2][sv];
                }
        }
        __syncthreads();
    }

    #pragma unroll
    for (int off = 16; off <= 32; off <<= 1) {
        float ov1 = __shfl_xor(v1, off); int oi1 = __shfl_xor(i1, off);
        float ov2 = __shfl_xor(v2, off); int oi2 = __shfl_xor(i2, off);
        if (ov1 < v1 || (ov1 == v1 && oi1 < i1)) {
            float tv = v1; int ti = i1; v1 = ov1; i1 = oi1; ov1 = tv; oi1 = ti;
            tv = v2; ti = i2; v2 = ov2; i2 = oi2; ov2 = tv; oi2 = ti;
        }
        if (ov1 < v2 || (ov1 == v2 && oi1 < i2)) { v2 = ov1; i2 = oi1; }
    }

    i1 = (i1 < 0) ? 0 : (i1 > NCODES - 1 ? NCODES - 1 : i1);
    i2 = (i2 < 0) ? 0 : (i2 > NCODES - 1 ? NCODES - 1 : i2);

    const float* cp1 = cb + (size_t)i1 * KDIM;
    const float* cp2 = cb + (size_t)i2 * KDIM;
    float da = 0.f, db = 0.f;
    #pragma unroll
    for (int s = 0; s < 8; ++s) {
        f32x4 h0 = *(const f32x4*)(hrow + s * 32 + g * 8);
        f32x4 h1 = *(const f32x4*)(hrow + s * 32 + g * 8 + 4);
        f32x4 a1 = *(const f32x4*)(cp1 + s * 32 + g * 8);
        f32x4 b1 = *(const f32x4*)(cp1 + s * 32 + g * 8 + 4);
        f32x4 a2 = *(const f32x4*)(cp2 + s * 32 + g * 8);
        f32x4 b2 = *(const f32x4*)(cp2 + s * 32 + g * 8 + 4);
        #pragma unroll
        for (int jj = 0; jj < 4; ++jj) {
            da = fmaf(a1[jj], h0[jj], da); da = fmaf(b1[jj], h1[jj], da);
            db = fmaf(a2[jj], h0[jj], db); db = fmaf(b2[jj], h1[jj], db);
        }
    }
    da += __shfl_xor(da, 16); da += __shfl_xor(da, 32);
    db += __shfl_xor(db, 16); db += __shfl_xor(db, 32);
    const float d2a = cnorm[i1] - 2.f * da;
    const float d2b = cnorm[i2] - 2.f * db;
    const int win = (d2a < d2b || (d2a == d2b && i1 < i2)) ? i1 : i2;

    const float* cw = cb + (size_t)win * KDIM;
    #pragma unroll
    for (int s = 0; s < 8; ++s) {
        *(f32x4*)(hrow + s * 32 + g * 8)     = *(const f32x4*)(cw + s * 32 + g * 8);
        *(f32x4*)(hrow + s * 32 + g * 8 + 4) = *(const f32x4*)(cw + s * 32 + g * 8 + 4);
    }
    if (g == 0) idx_out[n0 + row] = (float)win;
}

extern "C" void kernel_launch(void* const* d_in, const int* in_sizes, int n_in,
                              void* d_out, int out_size, void* d_ws, size_t ws_size,
                              hipStream_t stream) {
    (void)in_sizes; (void)n_in; (void)out_size;
    const float* x    = (const float*)d_in[0];
    const float* W    = (const float*)d_in[1];
    const float* bvec = (const float*)d_in[2];
    const float* cb   = (const float*)d_in[3];

    float* codes_out = (float*)d_out;                       // doubles as h buffer
    float* idx_out   = (float*)d_out + (size_t)NROWS * KDIM;

    // ws layout: cnorm[16KB] | recs[512KB, int] | cb_hi[2MB] | cb_lo[2MB] | wt[3x0.5MB]
    float* cnorm = (float*)d_ws;
    int*   recs  = (int*)((char*)d_ws + 16384);
    unsigned short* cb_hi = (unsigned short*)((char*)d_ws + 16384 + 524288);
    unsigned short* cb_lo = cb_hi + (size_t)NCODES * KDIM;
    unsigned short* wt_hi = cb_lo + (size_t)NCODES * KDIM;
    unsigned short* wt_md = wt_hi + (size_t)INDIM * KDIM;
    unsigned short* wt_lo = wt_md + (size_t)INDIM * KDIM;

    const size_t need_rec  = 16384 + 524288;
    const size_t need_cb   = need_rec + (size_t)NCODES * KDIM * 2 * sizeof(unsigned short);
    const size_t need_full = need_cb + (size_t)INDIM * KDIM * 3 * sizeof(unsigned short);

    const int use_split = (ws_size >= need_rec) ? 1 : 0;
    const int pre_cb    = (ws_size >= need_cb) ? 1 : 0;
    const int fast_g    = (ws_size >= need_full) ? 1 : 0;

    if (fast_g) {
        wprep_kernel<<<INDIM / 4, 256, 0, stream>>>(W, wt_hi, wt_md, wt_lo);
        gemm_mfma_kernel<<<NROWS / MG_ROWS, 256, 0, stream>>>(x, wt_hi, wt_md, wt_lo, bvec, codes_out);
    } else {
        gemm_fb_kernel<<<NROWS / G_ROWS, 256, 0, stream>>>(x, W, bvec, codes_out);
    }
    prep_kernel<<<NCODES / 4, 256, 0, stream>>>(cb, cnorm, cb_hi, cb_lo, pre_cb);

    if (use_split) {
        if (pre_cb)
            vq_partial_kernel<1><<<(NROWS / P_ROWS) * 4, 256, 0, stream>>>(codes_out, cb, cnorm, cb_hi, cb_lo, recs);
        else
            vq_partial_kernel<0><<<(NROWS / P_ROWS) * 4, 256, 0, stream>>>(codes_out, cb, cnorm, cb_hi, cb_lo, recs);
        vq_merge_kernel<<<NROWS / V_ROWS, 256, 0, stream>>>(codes_out, cb, cnorm, recs, idx_out);
    } else {
        if (pre_cb)
            vq_kernel<1><<<NROWS / V_ROWS, 256, 0, stream>>>(codes_out, cb, cnorm, cb_hi, cb_lo, idx_out);
        else
            vq_kernel<0><<<NROWS / V_ROWS, 256, 0, stream>>>(codes_out, cb, cnorm, cb_hi, cb_lo, idx_out);
    }
}

// Round 17
// 295.337 us; speedup vs baseline: 1.6519x; 1.0406x over previous
//
#include <hip/hip_runtime.h>

#define NROWS   16384
#define INDIM   1024
#define KDIM    256
#define NCODES  4096
#define G_ROWS  32       // rows per fallback-gemm block
#define V_ROWS  64       // rows per vq_partial / merge / fallback vq block
#define PSTEP   64       // vq_partial: steps of 16 codes (quarter = 1024 codes)
#define NSTEP   128      // full-scan vq fallback: steps of 32 codes

// vq_partial LDS: 2 buffers x (hi 4KB + lo 4KB)... per buffer: hi 4KB? -> 16 codes*256B = 4KB hi + 4KB lo
#define PVBUF   8192     // per double-buffer half: hi 4096 + lo 4096
// fallback vq LDS: 2 buffers x (hi 16KB + lo 16KB)
#define VBUF    32768

// gemm LDS: X 3x8KB ([s][rs][lane]) + W 3x32KB ([s][cidx][lane])
#define MG_ROWS 64
#define MG_KC   64
#define MG_NCH  (INDIM / MG_KC)   // 16
#define XP(p)   ((p) * 8192)
#define WP(p)   (24576 + (p) * 32768)
#define MG_LDS  122880

typedef float f32x4 __attribute__((ext_vector_type(4)));
typedef int   i32x2 __attribute__((ext_vector_type(2)));
typedef short short8 __attribute__((ext_vector_type(8)));
typedef unsigned short u16x8 __attribute__((ext_vector_type(8)));
typedef unsigned short u16x4 __attribute__((ext_vector_type(4)));

__device__ inline unsigned short f2bf(float f) {
    unsigned u = __builtin_bit_cast(unsigned, f);
    u = (u + 0x7fffu + ((u >> 16) & 1u)) >> 16;
    return (unsigned short)u;
}
__device__ inline float bf2f(unsigned short h) {
    unsigned u = ((unsigned)h) << 16;
    return __builtin_bit_cast(float, u);
}
__device__ inline f32x4 mfma16(u16x8 a, u16x8 b, f32x4 c) {
    return __builtin_amdgcn_mfma_f32_16x16x32_bf16(
        __builtin_bit_cast(short8, a), __builtin_bit_cast(short8, b), c, 0, 0, 0);
}

// async global->LDS DMA, 16B/lane; dest = wave-uniform base + lane*16 (HW-implicit)
__device__ inline void gload16(const void* g, void* l) {
    __builtin_amdgcn_global_load_lds(
        (const __attribute__((address_space(1))) unsigned int*)g,
        (__attribute__((address_space(3))) unsigned int*)l,
        16, 0, 0);
}

// ---------------- prep: W[1024][256] f32 -> W_T 3-way bf16 split [256][1024] ----------------
__global__ __launch_bounds__(256) void wprep_kernel(const float* __restrict__ W,
                                                    unsigned short* __restrict__ wt_hi,
                                                    unsigned short* __restrict__ wt_md,
                                                    unsigned short* __restrict__ wt_lo) {
    const int t = threadIdx.x;
    const int k = blockIdx.x * 4 + (t >> 6);
    const int c0 = (t & 63) * 4;
    f32x4 v = *(const f32x4*)(W + (size_t)k * KDIM + c0);
    #pragma unroll
    for (int i = 0; i < 4; ++i) {
        const unsigned short h = f2bf(v[i]);
        const float r1 = v[i] - bf2f(h);
        const unsigned short m = f2bf(r1);
        const unsigned short lo = f2bf(r1 - bf2f(m));
        wt_hi[(size_t)(c0 + i) * INDIM + k] = h;
        wt_md[(size_t)(c0 + i) * INDIM + k] = m;
        wt_lo[(size_t)(c0 + i) * INDIM + k] = lo;
    }
}

// ---------------- MFMA gemm: h = x@W + b (6-pass 3-way split, f32-class accuracy) ----------------
__global__ __launch_bounds__(256, 1) void gemm_mfma_kernel(const float* __restrict__ x,
                                                           const unsigned short* __restrict__ wt_hi,
                                                           const unsigned short* __restrict__ wt_md,
                                                           const unsigned short* __restrict__ wt_lo,
                                                           const float* __restrict__ bvec,
                                                           float* __restrict__ hbuf) {
    __shared__ __align__(16) char lds[MG_LDS];

    const int t  = threadIdx.x;
    const int w  = t >> 6;
    const int l  = t & 63;
    const int nl = l & 15;
    const int g  = l >> 4;
    const size_t n0 = (size_t)blockIdx.x * MG_ROWS;
    const int lb = l * 16;

    f32x4 acc[4][4];
    #pragma unroll
    for (int a = 0; a < 4; ++a)
        #pragma unroll
        for (int b = 0; b < 4; ++b) acc[a][b] = (f32x4){0.f, 0.f, 0.f, 0.f};

    for (int kc = 0; kc < MG_NCH; ++kc) {
        f32x4 xa[2], xb[2];
        #pragma unroll
        for (int c = 0; c < 2; ++c) {
            const int idx = w * 2 + c;
            const int sX = idx >> 2, rsX = idx & 3;
            const float* p = x + (n0 + rsX * 16 + nl) * INDIM + kc * MG_KC + sX * 32 + g * 8;
            xa[c] = *(const f32x4*)(p);
            xb[c] = *(const f32x4*)(p + 4);
        }
        u16x8 wh[8], wm[8], wl[8];
        #pragma unroll
        for (int ci = 0; ci < 4; ++ci)
            #pragma unroll
            for (int sW = 0; sW < 2; ++sW) {
                const int q = ci * 2 + sW;
                const size_t off = (size_t)((w * 4 + ci) * 16 + nl) * INDIM
                                 + kc * MG_KC + sW * 32 + g * 8;
                wh[q] = *(const u16x8*)(wt_hi + off);
                wm[q] = *(const u16x8*)(wt_md + off);
                wl[q] = *(const u16x8*)(wt_lo + off);
            }
        __syncthreads();

        #pragma unroll
        for (int c = 0; c < 2; ++c) {
            const int idx = w * 2 + c;
            const int sX = idx >> 2, rsX = idx & 3;
            u16x8 xh, xm, xl;
            #pragma unroll
            for (int e = 0; e < 4; ++e) {
                const float a0 = xa[c][e], a1 = xb[c][e];
                const unsigned short h0 = f2bf(a0);
                const float r10 = a0 - bf2f(h0);
                const unsigned short m0 = f2bf(r10);
                const unsigned short l0 = f2bf(r10 - bf2f(m0));
                const unsigned short h1 = f2bf(a1);
                const float r11 = a1 - bf2f(h1);
                const unsigned short m1 = f2bf(r11);
                const unsigned short l1 = f2bf(r11 - bf2f(m1));
                xh[e] = h0; xh[4+e] = h1;
                xm[e] = m0; xm[4+e] = m1;
                xl[e] = l0; xl[4+e] = l1;
            }
            const int base = (sX * 4 + rsX) * 1024 + lb;
            *(u16x8*)(lds + XP(0) + base) = xh;
            *(u16x8*)(lds + XP(1) + base) = xm;
            *(u16x8*)(lds + XP(2) + base) = xl;
        }
        #pragma unroll
        for (int ci = 0; ci < 4; ++ci)
            #pragma unroll
            for (int sW = 0; sW < 2; ++sW) {
                const int q = ci * 2 + sW;
                const int base = (sW * 16 + w * 4 + ci) * 1024 + lb;
                *(u16x8*)(lds + WP(0) + base) = wh[q];
                *(u16x8*)(lds + WP(1) + base) = wm[q];
                *(u16x8*)(lds + WP(2) + base) = wl[q];
            }
        __syncthreads();

        #pragma unroll
        for (int s = 0; s < 2; ++s) {
            u16x8 bh[4], bm[4], bl[4], ah[4], am[4], al[4];
            #pragma unroll
            for (int rs = 0; rs < 4; ++rs) {
                const int base = (s * 4 + rs) * 1024 + lb;
                bh[rs] = *(const u16x8*)(lds + XP(0) + base);
                bm[rs] = *(const u16x8*)(lds + XP(1) + base);
                bl[rs] = *(const u16x8*)(lds + XP(2) + base);
            }
            #pragma unroll
            for (int ct = 0; ct < 4; ++ct) {
                const int base = (s * 16 + w * 4 + ct) * 1024 + lb;
                ah[ct] = *(const u16x8*)(lds + WP(0) + base);
                am[ct] = *(const u16x8*)(lds + WP(1) + base);
                al[ct] = *(const u16x8*)(lds + WP(2) + base);
            }
            #pragma unroll
            for (int ct = 0; ct < 4; ++ct)
                #pragma unroll
                for (int rs = 0; rs < 4; ++rs) {
                    acc[ct][rs] = mfma16(ah[ct], bh[rs], acc[ct][rs]);
                    acc[ct][rs] = mfma16(ah[ct], bm[rs], acc[ct][rs]);
                    acc[ct][rs] = mfma16(am[ct], bh[rs], acc[ct][rs]);
                    acc[ct][rs] = mfma16(ah[ct], bl[rs], acc[ct][rs]);
                    acc[ct][rs] = mfma16(al[ct], bh[rs], acc[ct][rs]);
                    acc[ct][rs] = mfma16(am[ct], bm[rs], acc[ct][rs]);
                }
        }
    }

    #pragma unroll
    for (int ct = 0; ct < 4; ++ct) {
        float bv[4];
        #pragma unroll
        for (int r = 0; r < 4; ++r) bv[r] = bvec[w * 64 + ct * 16 + g * 4 + r];
        #pragma unroll
        for (int rs = 0; rs < 4; ++rs) {
            const size_t row = n0 + rs * 16 + nl;
            #pragma unroll
            for (int r = 0; r < 4; ++r)
                hbuf[row * KDIM + w * 64 + ct * 16 + g * 4 + r] = acc[ct][rs][r] + bv[r];
        }
    }
}

// ---------------- fallback f32 gemm ----------------
__global__ __launch_bounds__(256, 2) void gemm_fb_kernel(const float* __restrict__ x,
                                                         const float* __restrict__ W,
                                                         const float* __restrict__ bvec,
                                                         float* __restrict__ hbuf) {
    const int t  = threadIdx.x;
    const int cg = t & 15;
    const int rg = t >> 4;
    const size_t n0 = (size_t)blockIdx.x * G_ROWS;
    const int c0 = cg * 16;

    float acc[2][16];
    #pragma unroll
    for (int j = 0; j < 2; ++j)
        #pragma unroll
        for (int cc = 0; cc < 16; ++cc) acc[j][cc] = 0.f;

    for (int k4 = 0; k4 < INDIM / 4; ++k4) {
        const int k = k4 * 4;
        f32x4 xv[2];
        #pragma unroll
        for (int j = 0; j < 2; ++j)
            xv[j] = *(const f32x4*)(x + (n0 + rg + 16 * j) * INDIM + k);
        f32x4 wv[4][4];
        #pragma unroll
        for (int kk = 0; kk < 4; ++kk)
            #pragma unroll
            for (int q = 0; q < 4; ++q)
                wv[kk][q] = *(const f32x4*)(W + (size_t)(k + kk) * KDIM + c0 + 4 * q);
        #pragma unroll
        for (int j = 0; j < 2; ++j)
            #pragma unroll
            for (int kk = 0; kk < 4; ++kk) {
                const float xs = xv[j][kk];
                #pragma unroll
                for (int q = 0; q < 4; ++q)
                    #pragma unroll
                    for (int e = 0; e < 4; ++e)
                        acc[j][4*q+e] = fmaf(xs, wv[kk][q][e], acc[j][4*q+e]);
            }
    }
    #pragma unroll
    for (int j = 0; j < 2; ++j) {
        float* dst = hbuf + (n0 + rg + 16 * j) * KDIM + c0;
        #pragma unroll
        for (int q = 0; q < 4; ++q) {
            f32x4 v;
            #pragma unroll
            for (int e = 0; e < 4; ++e) v[e] = acc[j][4*q+e] + bvec[c0 + 4*q + e];
            *(f32x4*)(dst + 4*q) = v;
        }
    }
}

// ---------------- prep: cnorm + optional bf16 hi/lo split of cb ----------------
__global__ __launch_bounds__(256) void prep_kernel(const float* __restrict__ cb,
                                                   float* __restrict__ cnorm,
                                                   unsigned short* __restrict__ cb_hi,
                                                   unsigned short* __restrict__ cb_lo,
                                                   int do_split) {
    const int c    = blockIdx.x * 4 + (threadIdx.x >> 6);
    const int lane = threadIdx.x & 63;
    f32x4 v = ((const f32x4*)(cb + (size_t)c * KDIM))[lane];
    if (do_split) {
        u16x4 h4, l4;
        #pragma unroll
        for (int j = 0; j < 4; ++j) {
            unsigned short h = f2bf(v[j]);
            h4[j] = h;
            l4[j] = f2bf(v[j] - bf2f(h));
        }
        *(u16x4*)(cb_hi + (size_t)c * KDIM + lane * 4) = h4;
        *(u16x4*)(cb_lo + (size_t)c * KDIM + lane * 4) = l4;
    }
    float s = v[0]*v[0] + v[1]*v[1] + v[2]*v[2] + v[3]*v[3];
    #pragma unroll
    for (int off = 1; off < 64; off <<= 1) s += __shfl_xor(s, off);
    if (lane == 0) cnorm[c] = s;
}

// ===== vq partial: 64 rows/block (1 rowset/wave), quarter of codes, 16 codes/step ===========
// Small footprint: ~96-110 VGPR, 32 KB LDS -> 4-5 blocks/CU resident.
template<int PRE>
__global__ __launch_bounds__(256) void vq_partial_kernel(
    const float* __restrict__ hbuf,
    const float* __restrict__ cb,
    const float* __restrict__ cnorm,
    const unsigned short* __restrict__ cb_hi,
    const unsigned short* __restrict__ cb_lo,
    int* __restrict__ recs)                    // [NROWS][4] int2 {i1,i2}
{
    __shared__ __align__(16) char lds[4 * PVBUF];   // 2 buffers x (hi 8KB? no:) -> 32 KB total

    const int t  = threadIdx.x;
    const int w  = t >> 6;
    const int l  = t & 63;
    const int nl = l & 15;
    const int g  = l >> 4;
    const int lb = l * 16;
    const int bid  = blockIdx.x;
    const int quar = bid & 3;
    const int cbase = quar * 1024;
    const size_t n0 = (size_t)(bid >> 2) * V_ROWS;
    const int row = w * 16 + nl;

    // B-fragments for this lane's row (r11-proven construction)
    u16x8 bhi[8], bmid[8];
    {
        const float* hrow = hbuf + (n0 + row) * KDIM;
        #pragma unroll
        for (int s = 0; s < 8; ++s) {
            f32x4 a = *(const f32x4*)(hrow + s * 32 + g * 8);
            f32x4 b = *(const f32x4*)(hrow + s * 32 + g * 8 + 4);
            u16x8 uh, um;
            #pragma unroll
            for (int jj = 0; jj < 4; ++jj) {
                unsigned short h0 = f2bf(a[jj]); uh[jj]   = h0; um[jj]   = f2bf(a[jj] - bf2f(h0));
                unsigned short h1 = f2bf(b[jj]); uh[4+jj] = h1; um[4+jj] = f2bf(b[jj] - bf2f(h1));
            }
            bhi[s] = uh; bmid[s] = um;
        }
    }

    float v1 = 3.4e38f, v2 = 3.4e38f;
    int   i1 = 0, i2 = 0;

    u16x8 rh[2], rl[2];   // non-PRE only

    // buffer layout (per half, 16 KB): hi [16 codes x 1KB] at +0, lo at +8192
    // ---- prologue: stage step 0 into buffer 0; wave w covers chunks sc = w*2, w*2+1 ----
    if (PRE) {
        #pragma unroll
        for (int sv = 0; sv < 2; ++sv) {
            const int sc = w * 2 + sv;
            const size_t off = (size_t)(cbase + nl) * KDIM + (sc * 4 + g) * 8;
            gload16(cb_hi + off, lds + sc * 1024);
            gload16(cb_lo + off, lds + 8192 + sc * 1024);
        }
    } else {
        #pragma unroll
        for (int sv = 0; sv < 2; ++sv) {
            const int sc = w * 2 + sv;
            const float* p = cb + (size_t)(cbase + nl) * KDIM + (sc * 4 + g) * 8;
            f32x4 a = *(const f32x4*)(p);
            f32x4 b = *(const f32x4*)(p + 4);
            u16x8 uh, ul;
            #pragma unroll
            for (int jj = 0; jj < 4; ++jj) {
                unsigned short h0 = f2bf(a[jj]); uh[jj]   = h0; ul[jj]   = f2bf(a[jj] - bf2f(h0));
                unsigned short h1 = f2bf(b[jj]); uh[4+jj] = h1; ul[4+jj] = f2bf(b[jj] - bf2f(h1));
            }
            rh[sv] = uh; rl[sv] = ul;
        }
        #pragma unroll
        for (int sv = 0; sv < 2; ++sv) {
            const int sc = w * 2 + sv;
            *(u16x8*)(lds + sc * 1024 + lb) = rh[sv];
            *(u16x8*)(lds + 8192 + sc * 1024 + lb) = rl[sv];
        }
    }
    __syncthreads();

    for (int S = 0; S < PSTEP; ++S) {
        const int b = S & 1;
        char* nbuf = lds + (b ^ 1) * 16384;
        if (S + 1 < PSTEP) {
            if (PRE) {
                #pragma unroll
                for (int sv = 0; sv < 2; ++sv) {
                    const int sc = w * 2 + sv;
                    const size_t off = (size_t)(cbase + (S + 1) * 16 + nl) * KDIM + (sc * 4 + g) * 8;
                    gload16(cb_hi + off, nbuf + sc * 1024);
                    gload16(cb_lo + off, nbuf + 8192 + sc * 1024);
                }
            } else {
                #pragma unroll
                for (int sv = 0; sv < 2; ++sv) {
                    const int sc = w * 2 + sv;
                    const float* p = cb + (size_t)(cbase + (S + 1) * 16 + nl) * KDIM + (sc * 4 + g) * 8;
                    f32x4 a = *(const f32x4*)(p);
                    f32x4 bb = *(const f32x4*)(p + 4);
                    u16x8 uh, ul;
                    #pragma unroll
                    for (int jj = 0; jj < 4; ++jj) {
                        unsigned short h0 = f2bf(a[jj]);  uh[jj]   = h0; ul[jj]   = f2bf(a[jj] - bf2f(h0));
                        unsigned short h1 = f2bf(bb[jj]); uh[4+jj] = h1; ul[4+jj] = f2bf(bb[jj] - bf2f(h1));
                    }
                    rh[sv] = uh; rl[sv] = ul;
                }
            }
        }
        const f32x4 cn = *(const f32x4*)(cnorm + cbase + S * 16 + g * 4);
        {
            const char* buf = lds + b * 16384;
            f32x4 acc = {0.f, 0.f, 0.f, 0.f};
            #pragma unroll
            for (int s = 0; s < 8; ++s) {
                const int base = s * 1024 + lb;
                u16x8 ahi = *(const u16x8*)(buf + base);
                u16x8 alo = *(const u16x8*)(buf + 8192 + base);
                acc = mfma16(ahi, bhi[s],  acc);
                acc = mfma16(ahi, bmid[s], acc);
                acc = mfma16(alo, bhi[s],  acc);
            }
            #pragma unroll
            for (int r = 0; r < 4; ++r) {
                const int c = cbase + S * 16 + g * 4 + r;
                const float d2 = cn[r] - 2.0f * acc[r];
                if (d2 < v1)      { v2 = v1; i2 = i1; v1 = d2; i1 = c; }
                else if (d2 < v2) { v2 = d2; i2 = c; }
            }
        }
        __syncthreads();   // PRE: drains DMA (back buffer ready) + read-sync
        if (!PRE) {
            if (S + 1 < PSTEP) {
                #pragma unroll
                for (int sv = 0; sv < 2; ++sv) {
                    const int sc = w * 2 + sv;
                    *(u16x8*)(nbuf + sc * 1024 + lb) = rh[sv];
                    *(u16x8*)(nbuf + 8192 + sc * 1024 + lb) = rl[sv];
                }
            }
            __syncthreads();
        }
    }

    // merge top-2 across the 4 g-lane-groups — r7/r11-verbatim
    #pragma unroll
    for (int off = 16; off <= 32; off <<= 1) {
        float ov1 = __shfl_xor(v1, off); int oi1 = __shfl_xor(i1, off);
        float ov2 = __shfl_xor(v2, off); int oi2 = __shfl_xor(i2, off);
        if (ov1 < v1 || (ov1 == v1 && oi1 < i1)) {
            float tv = v1; int ti = i1; v1 = ov1; i1 = oi1; ov1 = tv; oi1 = ti;
            tv = v2; ti = i2; v2 = ov2; i2 = oi2; ov2 = tv; oi2 = ti;
        }
        if (ov1 < v2 || (ov1 == v2 && oi1 < i2)) { v2 = ov1; i2 = oi1; }
    }

    // write 8B index-pair record at [row][quar] (int-typed memory)
    if (g == 0) {
        i32x2 rec;
        rec[0] = i1; rec[1] = i2;
        *(i32x2*)(recs + ((n0 + row) * 4 + quar) * 2) = rec;
    }
}

// ====== vq merge: exact-refine ALL 8 candidates (4 quarters x top-2), gather, idx ===========
__global__ __launch_bounds__(256) void vq_merge_kernel(
    float* __restrict__ hbuf,
    const float* __restrict__ cb,
    const float* __restrict__ cnorm,
    const int* __restrict__ recs,
    float* __restrict__ idx_out)
{
    const int t  = threadIdx.x;
    const int w  = t >> 6;
    const int l  = t & 63;
    const int nl = l & 15;
    const int g  = l >> 4;
    const size_t n0 = (size_t)blockIdx.x * V_ROWS;
    const int row = w * 16 + nl;
    float* hrow = hbuf + (n0 + row) * KDIM;

    int cand[8];
    {
        const size_t rb = (n0 + row) * 8;
        #pragma unroll
        for (int q = 0; q < 4; ++q) {
            i32x2 rq = *(const i32x2*)(recs + rb + q * 2);
            int a = rq[0], b = rq[1];
            cand[2*q]   = (a < 0) ? 0 : (a > NCODES - 1 ? NCODES - 1 : a);
            cand[2*q+1] = (b < 0) ? 0 : (b > NCODES - 1 ? NCODES - 1 : b);
        }
    }

    f32x4 hreg[16];
    #pragma unroll
    for (int s = 0; s < 8; ++s) {
        hreg[2*s]   = *(const f32x4*)(hrow + s * 32 + g * 8);
        hreg[2*s+1] = *(const f32x4*)(hrow + s * 32 + g * 8 + 4);
    }

    float bestd = 3.4e38f;
    int   besti = 0x7fffffff;
    #pragma unroll
    for (int k = 0; k < 8; ++k) {
        const int ci = cand[k];
        const float* cp = cb + (size_t)ci * KDIM;
        float d = 0.f;
        #pragma unroll
        for (int s = 0; s < 8; ++s) {
            f32x4 a = *(const f32x4*)(cp + s * 32 + g * 8);
            f32x4 b = *(const f32x4*)(cp + s * 32 + g * 8 + 4);
            #pragma unroll
            for (int jj = 0; jj < 4; ++jj) {
                d = fmaf(a[jj], hreg[2*s][jj], d);
                d = fmaf(b[jj], hreg[2*s+1][jj], d);
            }
        }
        d += __shfl_xor(d, 16); d += __shfl_xor(d, 32);
        const float d2 = cnorm[ci] - 2.f * d;
        if (d2 < bestd || (d2 == bestd && ci < besti)) { bestd = d2; besti = ci; }
    }

    const float* cw = cb + (size_t)besti * KDIM;
    #pragma unroll
    for (int s = 0; s < 8; ++s) {
        *(f32x4*)(hrow + s * 32 + g * 8)     = *(const f32x4*)(cw + s * 32 + g * 8);
        *(f32x4*)(hrow + s * 32 + g * 8 + 4) = *(const f32x4*)(cw + s * 32 + g * 8 + 4);
    }
    if (g == 0) idx_out[n0 + row] = (float)besti;
}

// ---------------- r7-proven full-scan vq (fallback when ws too small for records) -----------
template<int PRE>
__global__ __launch_bounds__(256) void vq_kernel(
    float* __restrict__ hbuf,
    const float* __restrict__ cb,
    const float* __restrict__ cnorm,
    const unsigned short* __restrict__ cb_hi,
    const unsigned short* __restrict__ cb_lo,
    float* __restrict__ idx_out)
{
    __shared__ __align__(16) char lds[2 * VBUF];

    const int t  = threadIdx.x;
    const int w  = t >> 6;
    const int l  = t & 63;
    const int nl = l & 15;
    const int g  = l >> 4;
    const int lb = l * 16;
    const size_t n0 = (size_t)blockIdx.x * V_ROWS;
    const int row = w * 16 + nl;
    float* hrow = hbuf + (n0 + row) * KDIM;

    u16x8 bhi[8], bmid[8];
    #pragma unroll
    for (int s = 0; s < 8; ++s) {
        f32x4 a = *(const f32x4*)(hrow + s * 32 + g * 8);
        f32x4 b = *(const f32x4*)(hrow + s * 32 + g * 8 + 4);
        u16x8 uh, um;
        #pragma unroll
        for (int jj = 0; jj < 4; ++jj) {
            unsigned short h0 = f2bf(a[jj]); uh[jj]   = h0; um[jj]   = f2bf(a[jj] - bf2f(h0));
            unsigned short h1 = f2bf(b[jj]); uh[4+jj] = h1; um[4+jj] = f2bf(b[jj] - bf2f(h1));
        }
        bhi[s] = uh; bmid[s] = um;
    }

    float v1 = 3.4e38f, v2 = 3.4e38f;
    int   i1 = 0, i2 = 0;

    u16x8 rh[2][2], rl[2][2];

    #pragma unroll
    for (int t2 = 0; t2 < 2; ++t2)
        #pragma unroll
        for (int sv = 0; sv < 2; ++sv) {
            const int sst = w * 2 + sv;
            if (PRE) {
                const size_t off = (size_t)(t2 * 16 + nl) * KDIM + (sst * 4 + g) * 8;
                rh[t2][sv] = *(const u16x8*)(cb_hi + off);
                rl[t2][sv] = *(const u16x8*)(cb_lo + off);
            } else {
                const float* p = cb + (size_t)(t2 * 16 + nl) * KDIM + (sst * 4 + g) * 8;
                f32x4 a = *(const f32x4*)(p);
                f32x4 b = *(const f32x4*)(p + 4);
                u16x8 uh, ul;
                #pragma unroll
                for (int jj = 0; jj < 4; ++jj) {
                    unsigned short h0 = f2bf(a[jj]); uh[jj]   = h0; ul[jj]   = f2bf(a[jj] - bf2f(h0));
                    unsigned short h1 = f2bf(b[jj]); uh[4+jj] = h1; ul[4+jj] = f2bf(b[jj] - bf2f(h1));
                }
                rh[t2][sv] = uh; rl[t2][sv] = ul;
            }
        }
    #pragma unroll
    for (int t2 = 0; t2 < 2; ++t2)
        #pragma unroll
        for (int sv = 0; sv < 2; ++sv) {
            const int base = (t2 * 8 + w * 2 + sv) * 1024 + lb;
            *(u16x8*)(lds + base) = rh[t2][sv];
            *(u16x8*)(lds + 16384 + base) = rl[t2][sv];
        }
    __syncthreads();

    for (int S = 0; S < NSTEP; ++S) {
        const int b = S & 1;
        if (S + 1 < NSTEP) {
            #pragma unroll
            for (int t2 = 0; t2 < 2; ++t2)
                #pragma unroll
                for (int sv = 0; sv < 2; ++sv) {
                    const int sst = w * 2 + sv;
                    const int code = (S + 1) * 32 + t2 * 16 + nl;
                    if (PRE) {
                        const size_t off = (size_t)code * KDIM + (sst * 4 + g) * 8;
                        rh[t2][sv] = *(const u16x8*)(cb_hi + off);
                        rl[t2][sv] = *(const u16x8*)(cb_lo + off);
                    } else {
                        const float* p = cb + (size_t)code * KDIM + (sst * 4 + g) * 8;
                        f32x4 a = *(const f32x4*)(p);
                        f32x4 bb = *(const f32x4*)(p + 4);
                        u16x8 uh, ul;
                        #pragma unroll
                        for (int jj = 0; jj < 4; ++jj) {
                            unsigned short h0 = f2bf(a[jj]);  uh[jj]   = h0; ul[jj]   = f2bf(a[jj] - bf2f(h0));
                            unsigned short h1 = f2bf(bb[jj]); uh[4+jj] = h1; ul[4+jj] = f2bf(bb[jj] - bf2f(h1));
                        }
                        rh[t2][sv] = uh; rl[t2][sv] = ul;
                    }
                }
        }
        f32x4 cn0 = *(const f32x4*)(cnorm + S * 32 + g * 4);
        f32x4 cn1 = *(const f32x4*)(cnorm + S * 32 + 16 + g * 4);
        {
            const char* buf = lds + b * VBUF;
            #pragma unroll
            for (int t2 = 0; t2 < 2; ++t2) {
                f32x4 acc = {0.f, 0.f, 0.f, 0.f};
                #pragma unroll
                for (int s = 0; s < 8; ++s) {
                    const int base = (t2 * 8 + s) * 1024 + lb;
                    u16x8 ahi = *(const u16x8*)(buf + base);
                    u16x8 alo = *(const u16x8*)(buf + 16384 + base);
                    acc = mfma16(ahi, bhi[s],  acc);
                    acc = mfma16(ahi, bmid[s], acc);
                    acc = mfma16(alo, bhi[s],  acc);
                }
                const f32x4 cn = t2 ? cn1 : cn0;
                #pragma unroll
                for (int r = 0; r < 4; ++r) {
                    const float d2 = cn[r] - 2.0f * acc[r];
                    const int c = S * 32 + t2 * 16 + g * 4 + r;
                    if (d2 < v1)      { v2 = v1; i2 = i1; v1 = d2; i1 = c; }
                    else if (d2 < v2) { v2 = d2; i2 = c; }
                }
            }
        }
        __syncthreads();
        if (S + 1 < NSTEP) {
            char* nbuf = lds + (b ^ 1) * VBUF;
            #pragma unroll
            for (int t2 = 0; t2 < 2; ++t2)
                #pragma unroll
                for (int sv = 0; sv < 2; ++sv) {
                    const int base = (t2 * 8 + w * 2 + sv) * 1024 + lb;
                    *(u16x8*)(nbuf + base) = rh[t2][sv];
                    *(u16x8*)(nbuf + 16384 + base) = rl[t2][sv];
                }
        }
        __syncthreads();
    }

    #pragma unroll
    for (int off = 16; off <= 32; off <<= 1) {
        float ov1 = __shfl_xor(v1, off); int oi1 = __shfl_xor(i1, off);
        float ov2 = __shfl_xor(v2, off); int oi2 = __shfl_xor(i2, off);
        if (ov1 < v1 || (ov1 == v1 && oi1 < i1)) {
            float tv = v1; int ti = i1; v1 = ov1; i1 = oi1; ov1 = tv; oi1 = ti;
            tv = v2; ti = i2; v2 = ov2; i2 = oi2; ov2 = tv; oi2 = ti;
        }
        if (ov1 < v2 || (ov1 == v2 && oi1 < i2)) { v2 = ov1; i2 = oi1; }
    }

    i1 = (i1 < 0) ? 0 : (i1 > NCODES - 1 ? NCODES - 1 : i1);
    i2 = (i2 < 0) ? 0 : (i2 > NCODES - 1 ? NCODES - 1 : i2);

    const float* cp1 = cb + (size_t)i1 * KDIM;
    const float* cp2 = cb + (size_t)i2 * KDIM;
    float da = 0.f, db = 0.f;
    #pragma unroll
    for (int s = 0; s < 8; ++s) {
        f32x4 h0 = *(const f32x4*)(hrow + s * 32 + g * 8);
        f32x4 h1 = *(const f32x4*)(hrow + s * 32 + g * 8 + 4);
        f32x4 a1 = *(const f32x4*)(cp1 + s * 32 + g * 8);
        f32x4 b1 = *(const f32x4*)(cp1 + s * 32 + g * 8 + 4);
        f32x4 a2 = *(const f32x4*)(cp2 + s * 32 + g * 8);
        f32x4 b2 = *(const f32x4*)(cp2 + s * 32 + g * 8 + 4);
        #pragma unroll
        for (int jj = 0; jj < 4; ++jj) {
            da = fmaf(a1[jj], h0[jj], da); da = fmaf(b1[jj], h1[jj], da);
            db = fmaf(a2[jj], h0[jj], db); db = fmaf(b2[jj], h1[jj], db);
        }
    }
    da += __shfl_xor(da, 16); da += __shfl_xor(da, 32);
    db += __shfl_xor(db, 16); db += __shfl_xor(db, 32);
    const float d2a = cnorm[i1] - 2.f * da;
    const float d2b = cnorm[i2] - 2.f * db;
    const int win = (d2a < d2b || (d2a == d2b && i1 < i2)) ? i1 : i2;

    const float* cw = cb + (size_t)win * KDIM;
    #pragma unroll
    for (int s = 0; s < 8; ++s) {
        *(f32x4*)(hrow + s * 32 + g * 8)     = *(const f32x4*)(cw + s * 32 + g * 8);
        *(f32x4*)(hrow + s * 32 + g * 8 + 4) = *(const f32x4*)(cw + s * 32 + g * 8 + 4);
    }
    if (g == 0) idx_out[n0 + row] = (float)win;
}

extern "C" void kernel_launch(void* const* d_in, const int* in_sizes, int n_in,
                              void* d_out, int out_size, void* d_ws, size_t ws_size,
                              hipStream_t stream) {
    (void)in_sizes; (void)n_in; (void)out_size;
    const float* x    = (const float*)d_in[0];
    const float* W    = (const float*)d_in[1];
    const float* bvec = (const float*)d_in[2];
    const float* cb   = (const float*)d_in[3];

    float* codes_out = (float*)d_out;                       // doubles as h buffer
    float* idx_out   = (float*)d_out + (size_t)NROWS * KDIM;

    // ws layout: cnorm[16KB] | recs[512KB, int] | cb_hi[2MB] | cb_lo[2MB] | wt[3x0.5MB]
    float* cnorm = (float*)d_ws;
    int*   recs  = (int*)((char*)d_ws + 16384);
    unsigned short* cb_hi = (unsigned short*)((char*)d_ws + 16384 + 524288);
    unsigned short* cb_lo = cb_hi + (size_t)NCODES * KDIM;
    unsigned short* wt_hi = cb_lo + (size_t)NCODES * KDIM;
    unsigned short* wt_md = wt_hi + (size_t)INDIM * KDIM;
    unsigned short* wt_lo = wt_md + (size_t)INDIM * KDIM;

    const size_t need_rec  = 16384 + 524288;
    const size_t need_cb   = need_rec + (size_t)NCODES * KDIM * 2 * sizeof(unsigned short);
    const size_t need_full = need_cb + (size_t)INDIM * KDIM * 3 * sizeof(unsigned short);

    const int use_split = (ws_size >= need_rec) ? 1 : 0;
    const int pre_cb    = (ws_size >= need_cb) ? 1 : 0;
    const int fast_g    = (ws_size >= need_full) ? 1 : 0;

    if (fast_g) {
        wprep_kernel<<<INDIM / 4, 256, 0, stream>>>(W, wt_hi, wt_md, wt_lo);
        gemm_mfma_kernel<<<NROWS / MG_ROWS, 256, 0, stream>>>(x, wt_hi, wt_md, wt_lo, bvec, codes_out);
    } else {
        gemm_fb_kernel<<<NROWS / G_ROWS, 256, 0, stream>>>(x, W, bvec, codes_out);
    }
    prep_kernel<<<NCODES / 4, 256, 0, stream>>>(cb, cnorm, cb_hi, cb_lo, pre_cb);

    if (use_split) {
        if (pre_cb)
            vq_partial_kernel<1><<<(NROWS / V_ROWS) * 4, 256, 0, stream>>>(codes_out, cb, cnorm, cb_hi, cb_lo, recs);
        else
            vq_partial_kernel<0><<<(NROWS / V_ROWS) * 4, 256, 0, stream>>>(codes_out, cb, cnorm, cb_hi, cb_lo, recs);
        vq_merge_kernel<<<NROWS / V_ROWS, 256, 0, stream>>>(codes_out, cb, cnorm, recs, idx_out);
    } else {
        if (pre_cb)
            vq_kernel<1><<<NROWS / V_ROWS, 256, 0, stream>>>(codes_out, cb, cnorm, cb_hi, cb_lo, idx_out);
        else
            vq_kernel<0><<<NROWS / V_ROWS, 256, 0, stream>>>(codes_out, cb, cnorm, cb_hi, cb_lo, idx_out);
    }
}

// Round 18
// 286.980 us; speedup vs baseline: 1.7000x; 1.0291x over previous
//
#include <hip/hip_runtime.h>

#define NROWS   16384
#define INDIM   1024
#define KDIM    256
#define NCODES  4096
#define G_ROWS  32       // rows per fallback-gemm block
#define V_ROWS  64       // rows per fallback vq / merge block
#define P_ROWS  128      // rows per vq_partial block
#define NSTEP   128      // full-scan vq: steps of 32 codes

// vq LDS: 2 buffers x (hi 16KB + lo 16KB); [t2][s][lane] lane-linear
#define VBUF    32768

// gemm LDS: X 3x8KB ([s][rs][lane]) + W 3x32KB ([s][cidx][lane])
#define MG_ROWS 64
#define MG_KC   64
#define MG_NCH  (INDIM / MG_KC)   // 16
#define XP(p)   ((p) * 8192)
#define WP(p)   (24576 + (p) * 32768)
#define MG_LDS  122880

typedef float f32x4 __attribute__((ext_vector_type(4)));
typedef int   i32x2 __attribute__((ext_vector_type(2)));
typedef short short8 __attribute__((ext_vector_type(8)));
typedef unsigned short u16x8 __attribute__((ext_vector_type(8)));
typedef unsigned short u16x4 __attribute__((ext_vector_type(4)));

__device__ inline unsigned short f2bf(float f) {
    unsigned u = __builtin_bit_cast(unsigned, f);
    u = (u + 0x7fffu + ((u >> 16) & 1u)) >> 16;
    return (unsigned short)u;
}
__device__ inline float bf2f(unsigned short h) {
    unsigned u = ((unsigned)h) << 16;
    return __builtin_bit_cast(float, u);
}
__device__ inline f32x4 mfma16(u16x8 a, u16x8 b, f32x4 c) {
    return __builtin_amdgcn_mfma_f32_16x16x32_bf16(
        __builtin_bit_cast(short8, a), __builtin_bit_cast(short8, b), c, 0, 0, 0);
}

// async global->LDS DMA, 16B/lane; dest = wave-uniform base + lane*16 (HW-implicit)
__device__ inline void gload16(const void* g, void* l) {
    __builtin_amdgcn_global_load_lds(
        (const __attribute__((address_space(1))) unsigned int*)g,
        (__attribute__((address_space(3))) unsigned int*)l,
        16, 0, 0);
}

// ---------------- prep: W[1024][256] f32 -> W_T 3-way bf16 split [256][1024] ----------------
__global__ __launch_bounds__(256) void wprep_kernel(const float* __restrict__ W,
                                                    unsigned short* __restrict__ wt_hi,
                                                    unsigned short* __restrict__ wt_md,
                                                    unsigned short* __restrict__ wt_lo) {
    const int t = threadIdx.x;
    const int k = blockIdx.x * 4 + (t >> 6);
    const int c0 = (t & 63) * 4;
    f32x4 v = *(const f32x4*)(W + (size_t)k * KDIM + c0);
    #pragma unroll
    for (int i = 0; i < 4; ++i) {
        const unsigned short h = f2bf(v[i]);
        const float r1 = v[i] - bf2f(h);
        const unsigned short m = f2bf(r1);
        const unsigned short lo = f2bf(r1 - bf2f(m));
        wt_hi[(size_t)(c0 + i) * INDIM + k] = h;
        wt_md[(size_t)(c0 + i) * INDIM + k] = m;
        wt_lo[(size_t)(c0 + i) * INDIM + k] = lo;
    }
}

// ---------------- MFMA gemm: h = x@W + b (6-pass 3-way split, f32-class accuracy) ----------------
__global__ __launch_bounds__(256, 1) void gemm_mfma_kernel(const float* __restrict__ x,
                                                           const unsigned short* __restrict__ wt_hi,
                                                           const unsigned short* __restrict__ wt_md,
                                                           const unsigned short* __restrict__ wt_lo,
                                                           const float* __restrict__ bvec,
                                                           float* __restrict__ hbuf) {
    __shared__ __align__(16) char lds[MG_LDS];

    const int t  = threadIdx.x;
    const int w  = t >> 6;
    const int l  = t & 63;
    const int nl = l & 15;
    const int g  = l >> 4;
    const size_t n0 = (size_t)blockIdx.x * MG_ROWS;
    const int lb = l * 16;

    f32x4 acc[4][4];
    #pragma unroll
    for (int a = 0; a < 4; ++a)
        #pragma unroll
        for (int b = 0; b < 4; ++b) acc[a][b] = (f32x4){0.f, 0.f, 0.f, 0.f};

    for (int kc = 0; kc < MG_NCH; ++kc) {
        f32x4 xa[2], xb[2];
        #pragma unroll
        for (int c = 0; c < 2; ++c) {
            const int idx = w * 2 + c;
            const int sX = idx >> 2, rsX = idx & 3;
            const float* p = x + (n0 + rsX * 16 + nl) * INDIM + kc * MG_KC + sX * 32 + g * 8;
            xa[c] = *(const f32x4*)(p);
            xb[c] = *(const f32x4*)(p + 4);
        }
        u16x8 wh[8], wm[8], wl[8];
        #pragma unroll
        for (int ci = 0; ci < 4; ++ci)
            #pragma unroll
            for (int sW = 0; sW < 2; ++sW) {
                const int q = ci * 2 + sW;
                const size_t off = (size_t)((w * 4 + ci) * 16 + nl) * INDIM
                                 + kc * MG_KC + sW * 32 + g * 8;
                wh[q] = *(const u16x8*)(wt_hi + off);
                wm[q] = *(const u16x8*)(wt_md + off);
                wl[q] = *(const u16x8*)(wt_lo + off);
            }
        __syncthreads();

        #pragma unroll
        for (int c = 0; c < 2; ++c) {
            const int idx = w * 2 + c;
            const int sX = idx >> 2, rsX = idx & 3;
            u16x8 xh, xm, xl;
            #pragma unroll
            for (int e = 0; e < 4; ++e) {
                const float a0 = xa[c][e], a1 = xb[c][e];
                const unsigned short h0 = f2bf(a0);
                const float r10 = a0 - bf2f(h0);
                const unsigned short m0 = f2bf(r10);
                const unsigned short l0 = f2bf(r10 - bf2f(m0));
                const unsigned short h1 = f2bf(a1);
                const float r11 = a1 - bf2f(h1);
                const unsigned short m1 = f2bf(r11);
                const unsigned short l1 = f2bf(r11 - bf2f(m1));
                xh[e] = h0; xh[4+e] = h1;
                xm[e] = m0; xm[4+e] = m1;
                xl[e] = l0; xl[4+e] = l1;
            }
            const int base = (sX * 4 + rsX) * 1024 + lb;
            *(u16x8*)(lds + XP(0) + base) = xh;
            *(u16x8*)(lds + XP(1) + base) = xm;
            *(u16x8*)(lds + XP(2) + base) = xl;
        }
        #pragma unroll
        for (int ci = 0; ci < 4; ++ci)
            #pragma unroll
            for (int sW = 0; sW < 2; ++sW) {
                const int q = ci * 2 + sW;
                const int base = (sW * 16 + w * 4 + ci) * 1024 + lb;
                *(u16x8*)(lds + WP(0) + base) = wh[q];
                *(u16x8*)(lds + WP(1) + base) = wm[q];
                *(u16x8*)(lds + WP(2) + base) = wl[q];
            }
        __syncthreads();

        #pragma unroll
        for (int s = 0; s < 2; ++s) {
            u16x8 bh[4], bm[4], bl[4], ah[4], am[4], al[4];
            #pragma unroll
            for (int rs = 0; rs < 4; ++rs) {
                const int base = (s * 4 + rs) * 1024 + lb;
                bh[rs] = *(const u16x8*)(lds + XP(0) + base);
                bm[rs] = *(const u16x8*)(lds + XP(1) + base);
                bl[rs] = *(const u16x8*)(lds + XP(2) + base);
            }
            #pragma unroll
            for (int ct = 0; ct < 4; ++ct) {
                const int base = (s * 16 + w * 4 + ct) * 1024 + lb;
                ah[ct] = *(const u16x8*)(lds + WP(0) + base);
                am[ct] = *(const u16x8*)(lds + WP(1) + base);
                al[ct] = *(const u16x8*)(lds + WP(2) + base);
            }
            #pragma unroll
            for (int ct = 0; ct < 4; ++ct)
                #pragma unroll
                for (int rs = 0; rs < 4; ++rs) {
                    acc[ct][rs] = mfma16(ah[ct], bh[rs], acc[ct][rs]);
                    acc[ct][rs] = mfma16(ah[ct], bm[rs], acc[ct][rs]);
                    acc[ct][rs] = mfma16(am[ct], bh[rs], acc[ct][rs]);
                    acc[ct][rs] = mfma16(ah[ct], bl[rs], acc[ct][rs]);
                    acc[ct][rs] = mfma16(al[ct], bh[rs], acc[ct][rs]);
                    acc[ct][rs] = mfma16(am[ct], bm[rs], acc[ct][rs]);
                }
        }
    }

    #pragma unroll
    for (int ct = 0; ct < 4; ++ct) {
        float bv[4];
        #pragma unroll
        for (int r = 0; r < 4; ++r) bv[r] = bvec[w * 64 + ct * 16 + g * 4 + r];
        #pragma unroll
        for (int rs = 0; rs < 4; ++rs) {
            const size_t row = n0 + rs * 16 + nl;
            #pragma unroll
            for (int r = 0; r < 4; ++r)
                hbuf[row * KDIM + w * 64 + ct * 16 + g * 4 + r] = acc[ct][rs][r] + bv[r];
        }
    }
}

// ---------------- fallback f32 gemm ----------------
__global__ __launch_bounds__(256, 2) void gemm_fb_kernel(const float* __restrict__ x,
                                                         const float* __restrict__ W,
                                                         const float* __restrict__ bvec,
                                                         float* __restrict__ hbuf) {
    const int t  = threadIdx.x;
    const int cg = t & 15;
    const int rg = t >> 4;
    const size_t n0 = (size_t)blockIdx.x * G_ROWS;
    const int c0 = cg * 16;

    float acc[2][16];
    #pragma unroll
    for (int j = 0; j < 2; ++j)
        #pragma unroll
        for (int cc = 0; cc < 16; ++cc) acc[j][cc] = 0.f;

    for (int k4 = 0; k4 < INDIM / 4; ++k4) {
        const int k = k4 * 4;
        f32x4 xv[2];
        #pragma unroll
        for (int j = 0; j < 2; ++j)
            xv[j] = *(const f32x4*)(x + (n0 + rg + 16 * j) * INDIM + k);
        f32x4 wv[4][4];
        #pragma unroll
        for (int kk = 0; kk < 4; ++kk)
            #pragma unroll
            for (int q = 0; q < 4; ++q)
                wv[kk][q] = *(const f32x4*)(W + (size_t)(k + kk) * KDIM + c0 + 4 * q);
        #pragma unroll
        for (int j = 0; j < 2; ++j)
            #pragma unroll
            for (int kk = 0; kk < 4; ++kk) {
                const float xs = xv[j][kk];
                #pragma unroll
                for (int q = 0; q < 4; ++q)
                    #pragma unroll
                    for (int e = 0; e < 4; ++e)
                        acc[j][4*q+e] = fmaf(xs, wv[kk][q][e], acc[j][4*q+e]);
            }
    }
    #pragma unroll
    for (int j = 0; j < 2; ++j) {
        float* dst = hbuf + (n0 + rg + 16 * j) * KDIM + c0;
        #pragma unroll
        for (int q = 0; q < 4; ++q) {
            f32x4 v;
            #pragma unroll
            for (int e = 0; e < 4; ++e) v[e] = acc[j][4*q+e] + bvec[c0 + 4*q + e];
            *(f32x4*)(dst + 4*q) = v;
        }
    }
}

// ---------------- prep: cnorm + optional bf16 hi/lo split of cb ----------------
__global__ __launch_bounds__(256) void prep_kernel(const float* __restrict__ cb,
                                                   float* __restrict__ cnorm,
                                                   unsigned short* __restrict__ cb_hi,
                                                   unsigned short* __restrict__ cb_lo,
                                                   int do_split) {
    const int c    = blockIdx.x * 4 + (threadIdx.x >> 6);
    const int lane = threadIdx.x & 63;
    f32x4 v = ((const f32x4*)(cb + (size_t)c * KDIM))[lane];
    if (do_split) {
        u16x4 h4, l4;
        #pragma unroll
        for (int j = 0; j < 4; ++j) {
            unsigned short h = f2bf(v[j]);
            h4[j] = h;
            l4[j] = f2bf(v[j] - bf2f(h));
        }
        *(u16x4*)(cb_hi + (size_t)c * KDIM + lane * 4) = h4;
        *(u16x4*)(cb_lo + (size_t)c * KDIM + lane * 4) = l4;
    }
    float s = v[0]*v[0] + v[1]*v[1] + v[2]*v[2] + v[3]*v[3];
    #pragma unroll
    for (int off = 1; off < 64; off <<= 1) s += __shfl_xor(s, off);
    if (lane == 0) cnorm[c] = s;
}

// ======= vq partial: 128 rows/block, half of codes, async gload_lds staging (PRE) ========
template<int PRE>
__global__ __launch_bounds__(256, 2) void vq_partial_kernel(
    const float* __restrict__ hbuf,
    const float* __restrict__ cb,
    const float* __restrict__ cnorm,
    const unsigned short* __restrict__ cb_hi,
    const unsigned short* __restrict__ cb_lo,
    int* __restrict__ recs)                    // [NROWS][4] int2 {i1,i2} (halves use slots 0,1)
{
    __shared__ __align__(16) char lds[2 * VBUF];

    const int t  = threadIdx.x;
    const int w  = t >> 6;
    const int l  = t & 63;
    const int nl = l & 15;
    const int g  = l >> 4;
    const int lb = l * 16;
    const int bid  = blockIdx.x;
    const int half = bid & 1;
    const int S0   = half * 64;
    const size_t n0 = (size_t)(bid >> 1) * P_ROWS;

    // B-fragments for 2 row-sets: rows w*32 + rset*16 + nl
    u16x8 bhi[2][8], bmid[2][8];
    #pragma unroll
    for (int rset = 0; rset < 2; ++rset) {
        const float* hrow = hbuf + (n0 + w * 32 + rset * 16 + nl) * KDIM;
        #pragma unroll
        for (int s = 0; s < 8; ++s) {
            f32x4 a = *(const f32x4*)(hrow + s * 32 + g * 8);
            f32x4 b = *(const f32x4*)(hrow + s * 32 + g * 8 + 4);
            u16x8 uh, um;
            #pragma unroll
            for (int jj = 0; jj < 4; ++jj) {
                unsigned short h0 = f2bf(a[jj]); uh[jj]   = h0; um[jj]   = f2bf(a[jj] - bf2f(h0));
                unsigned short h1 = f2bf(b[jj]); uh[4+jj] = h1; um[4+jj] = f2bf(b[jj] - bf2f(h1));
            }
            bhi[rset][s] = uh; bmid[rset][s] = um;
        }
    }

    float v1[2] = {3.4e38f, 3.4e38f}, v2[2] = {3.4e38f, 3.4e38f};
    int   i1[2] = {0, 0},            i2[2] = {0, 0};

    u16x8 rh[2], rl[2];   // non-PRE only (per t2 temp reused)
    u16x8 rh2[2], rl2[2];

    // ---- prologue: stage step S0 into buffer 0 ----
    if (PRE) {
        #pragma unroll
        for (int t2 = 0; t2 < 2; ++t2)
            #pragma unroll
            for (int sv = 0; sv < 2; ++sv) {
                const int sst = w * 2 + sv;
                const int code = S0 * 32 + t2 * 16 + nl;
                const size_t off = (size_t)code * KDIM + (sst * 4 + g) * 8;
                const int base = (t2 * 8 + w * 2 + sv) * 1024;   // wave-uniform; HW adds lane*16
                gload16(cb_hi + off, lds + base);
                gload16(cb_lo + off, lds + 16384 + base);
            }
    } else {
        #pragma unroll
        for (int t2 = 0; t2 < 2; ++t2)
            #pragma unroll
            for (int sv = 0; sv < 2; ++sv) {
                const int sst = w * 2 + sv;
                const int code = S0 * 32 + t2 * 16 + nl;
                const float* p = cb + (size_t)code * KDIM + (sst * 4 + g) * 8;
                f32x4 a = *(const f32x4*)(p);
                f32x4 b = *(const f32x4*)(p + 4);
                u16x8 uh, ul;
                #pragma unroll
                for (int jj = 0; jj < 4; ++jj) {
                    unsigned short h0 = f2bf(a[jj]); uh[jj]   = h0; ul[jj]   = f2bf(a[jj] - bf2f(h0));
                    unsigned short h1 = f2bf(b[jj]); uh[4+jj] = h1; ul[4+jj] = f2bf(b[jj] - bf2f(h1));
                }
                if (t2 == 0) { rh[sv] = uh; rl[sv] = ul; } else { rh2[sv] = uh; rl2[sv] = ul; }
            }
        #pragma unroll
        for (int t2 = 0; t2 < 2; ++t2)
            #pragma unroll
            for (int sv = 0; sv < 2; ++sv) {
                const int base = (t2 * 8 + w * 2 + sv) * 1024 + lb;
                *(u16x8*)(lds + base) = t2 == 0 ? rh[sv] : rh2[sv];
                *(u16x8*)(lds + 16384 + base) = t2 == 0 ? rl[sv] : rl2[sv];
            }
    }
    __syncthreads();

    for (int S = S0; S < S0 + 64; ++S) {
        const int b = S & 1;
        char* nbuf = lds + (b ^ 1) * VBUF;
        if (S + 1 < S0 + 64) {
            if (PRE) {
                #pragma unroll
                for (int t2 = 0; t2 < 2; ++t2)
                    #pragma unroll
                    for (int sv = 0; sv < 2; ++sv) {
                        const int sst = w * 2 + sv;
                        const int code = (S + 1) * 32 + t2 * 16 + nl;
                        const size_t off = (size_t)code * KDIM + (sst * 4 + g) * 8;
                        const int base = (t2 * 8 + w * 2 + sv) * 1024;
                        gload16(cb_hi + off, nbuf + base);
                        gload16(cb_lo + off, nbuf + 16384 + base);
                    }
            } else {
                #pragma unroll
                for (int t2 = 0; t2 < 2; ++t2)
                    #pragma unroll
                    for (int sv = 0; sv < 2; ++sv) {
                        const int sst = w * 2 + sv;
                        const int code = (S + 1) * 32 + t2 * 16 + nl;
                        const float* p = cb + (size_t)code * KDIM + (sst * 4 + g) * 8;
                        f32x4 a = *(const f32x4*)(p);
                        f32x4 bb = *(const f32x4*)(p + 4);
                        u16x8 uh, ul;
                        #pragma unroll
                        for (int jj = 0; jj < 4; ++jj) {
                            unsigned short h0 = f2bf(a[jj]);  uh[jj]   = h0; ul[jj]   = f2bf(a[jj] - bf2f(h0));
                            unsigned short h1 = f2bf(bb[jj]); uh[4+jj] = h1; ul[4+jj] = f2bf(bb[jj] - bf2f(h1));
                        }
                        if (t2 == 0) { rh[sv] = uh; rl[sv] = ul; } else { rh2[sv] = uh; rl2[sv] = ul; }
                    }
            }
        }
        f32x4 cn0 = *(const f32x4*)(cnorm + S * 32 + g * 4);
        f32x4 cn1 = *(const f32x4*)(cnorm + S * 32 + 16 + g * 4);
        {
            const char* buf = lds + b * VBUF;
            #pragma unroll
            for (int t2 = 0; t2 < 2; ++t2) {
                f32x4 acc0 = {0.f, 0.f, 0.f, 0.f};
                f32x4 acc1 = {0.f, 0.f, 0.f, 0.f};
                #pragma unroll
                for (int s = 0; s < 8; ++s) {
                    const int base = (t2 * 8 + s) * 1024 + lb;
                    u16x8 ahi = *(const u16x8*)(buf + base);
                    u16x8 alo = *(const u16x8*)(buf + 16384 + base);
                    acc0 = mfma16(ahi, bhi[0][s],  acc0);
                    acc0 = mfma16(ahi, bmid[0][s], acc0);
                    acc0 = mfma16(alo, bhi[0][s],  acc0);
                    acc1 = mfma16(ahi, bhi[1][s],  acc1);
                    acc1 = mfma16(ahi, bmid[1][s], acc1);
                    acc1 = mfma16(alo, bhi[1][s],  acc1);
                }
                const f32x4 cn = t2 ? cn1 : cn0;
                #pragma unroll
                for (int r = 0; r < 4; ++r) {
                    const int c = S * 32 + t2 * 16 + g * 4 + r;
                    const float d0 = cn[r] - 2.0f * acc0[r];
                    if (d0 < v1[0])      { v2[0] = v1[0]; i2[0] = i1[0]; v1[0] = d0; i1[0] = c; }
                    else if (d0 < v2[0]) { v2[0] = d0; i2[0] = c; }
                    const float d1 = cn[r] - 2.0f * acc1[r];
                    if (d1 < v1[1])      { v2[1] = v1[1]; i2[1] = i1[1]; v1[1] = d1; i1[1] = c; }
                    else if (d1 < v2[1]) { v2[1] = d1; i2[1] = c; }
                }
            }
        }
        __syncthreads();   // PRE: drains DMA (back buffer ready) + read-sync
        if (!PRE) {
            if (S + 1 < S0 + 64) {
                #pragma unroll
                for (int t2 = 0; t2 < 2; ++t2)
                    #pragma unroll
                    for (int sv = 0; sv < 2; ++sv) {
                        const int base = (t2 * 8 + w * 2 + sv) * 1024 + lb;
                        *(u16x8*)(nbuf + base) = t2 == 0 ? rh[sv] : rh2[sv];
                        *(u16x8*)(nbuf + 16384 + base) = t2 == 0 ? rl[sv] : rl2[sv];
                    }
            }
            __syncthreads();
        }
    }

    // merge top-2 across the 4 g-lane-groups for each row-set
    #pragma unroll
    for (int rset = 0; rset < 2; ++rset) {
        #pragma unroll
        for (int off = 16; off <= 32; off <<= 1) {
            float ov1 = __shfl_xor(v1[rset], off); int oi1 = __shfl_xor(i1[rset], off);
            float ov2 = __shfl_xor(v2[rset], off); int oi2 = __shfl_xor(i2[rset], off);
            if (ov1 < v1[rset] || (ov1 == v1[rset] && oi1 < i1[rset])) {
                float tv = v1[rset]; int ti = i1[rset]; v1[rset] = ov1; i1[rset] = oi1; ov1 = tv; oi1 = ti;
                tv = v2[rset]; ti = i2[rset]; v2[rset] = ov2; i2[rset] = oi2; ov2 = tv; oi2 = ti;
            }
            if (ov1 < v2[rset] || (ov1 == v2[rset] && oi1 < i2[rset])) { v2[rset] = ov1; i2[rset] = oi1; }
        }
    }

    // write 8B index-pair record at [row][half]
    if (g == 0) {
        #pragma unroll
        for (int rset = 0; rset < 2; ++rset) {
            i32x2 rec;
            rec[0] = i1[rset]; rec[1] = i2[rset];
            const size_t row = n0 + w * 32 + rset * 16 + nl;
            *(i32x2*)(recs + (row * 4 + half) * 2) = rec;
        }
    }
}

// ====== vq merge: exact-refine 4 candidates (2 halves x top-2), gather, idx =================
__global__ __launch_bounds__(256) void vq_merge_kernel(
    float* __restrict__ hbuf,
    const float* __restrict__ cb,
    const float* __restrict__ cnorm,
    const int* __restrict__ recs,
    float* __restrict__ idx_out)
{
    const int t  = threadIdx.x;
    const int w  = t >> 6;
    const int l  = t & 63;
    const int nl = l & 15;
    const int g  = l >> 4;
    const size_t n0 = (size_t)blockIdx.x * V_ROWS;
    const int row = w * 16 + nl;
    float* hrow = hbuf + (n0 + row) * KDIM;

    int cand[4];
    {
        const size_t rb = (n0 + row) * 8;
        #pragma unroll
        for (int q = 0; q < 2; ++q) {
            i32x2 rq = *(const i32x2*)(recs + rb + q * 2);
            int a = rq[0], b = rq[1];
            cand[2*q]   = (a < 0) ? 0 : (a > NCODES - 1 ? NCODES - 1 : a);
            cand[2*q+1] = (b < 0) ? 0 : (b > NCODES - 1 ? NCODES - 1 : b);
        }
    }

    f32x4 hreg[16];
    #pragma unroll
    for (int s = 0; s < 8; ++s) {
        hreg[2*s]   = *(const f32x4*)(hrow + s * 32 + g * 8);
        hreg[2*s+1] = *(const f32x4*)(hrow + s * 32 + g * 8 + 4);
    }

    float bestd = 3.4e38f;
    int   besti = 0x7fffffff;
    #pragma unroll
    for (int k = 0; k < 4; ++k) {
        const int ci = cand[k];
        const float* cp = cb + (size_t)ci * KDIM;
        float d = 0.f;
        #pragma unroll
        for (int s = 0; s < 8; ++s) {
            f32x4 a = *(const f32x4*)(cp + s * 32 + g * 8);
            f32x4 b = *(const f32x4*)(cp + s * 32 + g * 8 + 4);
            #pragma unroll
            for (int jj = 0; jj < 4; ++jj) {
                d = fmaf(a[jj], hreg[2*s][jj], d);
                d = fmaf(b[jj], hreg[2*s+1][jj], d);
            }
        }
        d += __shfl_xor(d, 16); d += __shfl_xor(d, 32);
        const float d2 = cnorm[ci] - 2.f * d;
        if (d2 < bestd || (d2 == bestd && ci < besti)) { bestd = d2; besti = ci; }
    }

    const float* cw = cb + (size_t)besti * KDIM;
    #pragma unroll
    for (int s = 0; s < 8; ++s) {
        *(f32x4*)(hrow + s * 32 + g * 8)     = *(const f32x4*)(cw + s * 32 + g * 8);
        *(f32x4*)(hrow + s * 32 + g * 8 + 4) = *(const f32x4*)(cw + s * 32 + g * 8 + 4);
    }
    if (g == 0) idx_out[n0 + row] = (float)besti;
}

// ---------------- r7-proven full-scan vq (fallback when ws too small for records) -----------
template<int PRE>
__global__ __launch_bounds__(256) void vq_kernel(
    float* __restrict__ hbuf,
    const float* __restrict__ cb,
    const float* __restrict__ cnorm,
    const unsigned short* __restrict__ cb_hi,
    const unsigned short* __restrict__ cb_lo,
    float* __restrict__ idx_out)
{
    __shared__ __align__(16) char lds[2 * VBUF];

    const int t  = threadIdx.x;
    const int w  = t >> 6;
    const int l  = t & 63;
    const int nl = l & 15;
    const int g  = l >> 4;
    const int lb = l * 16;
    const size_t n0 = (size_t)blockIdx.x * V_ROWS;
    const int row = w * 16 + nl;
    float* hrow = hbuf + (n0 + row) * KDIM;

    u16x8 bhi[8], bmid[8];
    #pragma unroll
    for (int s = 0; s < 8; ++s) {
        f32x4 a = *(const f32x4*)(hrow + s * 32 + g * 8);
        f32x4 b = *(const f32x4*)(hrow + s * 32 + g * 8 + 4);
        u16x8 uh, um;
        #pragma unroll
        for (int jj = 0; jj < 4; ++jj) {
            unsigned short h0 = f2bf(a[jj]); uh[jj]   = h0; um[jj]   = f2bf(a[jj] - bf2f(h0));
            unsigned short h1 = f2bf(b[jj]); uh[4+jj] = h1; um[4+jj] = f2bf(b[jj] - bf2f(h1));
        }
        bhi[s] = uh; bmid[s] = um;
    }

    float v1 = 3.4e38f, v2 = 3.4e38f;
    int   i1 = 0, i2 = 0;

    u16x8 rh[2][2], rl[2][2];

    #pragma unroll
    for (int t2 = 0; t2 < 2; ++t2)
        #pragma unroll
        for (int sv = 0; sv < 2; ++sv) {
            const int sst = w * 2 + sv;
            if (PRE) {
                const size_t off = (size_t)(t2 * 16 + nl) * KDIM + (sst * 4 + g) * 8;
                rh[t2][sv] = *(const u16x8*)(cb_hi + off);
                rl[t2][sv] = *(const u16x8*)(cb_lo + off);
            } else {
                const float* p = cb + (size_t)(t2 * 16 + nl) * KDIM + (sst * 4 + g) * 8;
                f32x4 a = *(const f32x4*)(p);
                f32x4 b = *(const f32x4*)(p + 4);
                u16x8 uh, ul;
                #pragma unroll
                for (int jj = 0; jj < 4; ++jj) {
                    unsigned short h0 = f2bf(a[jj]); uh[jj]   = h0; ul[jj]   = f2bf(a[jj] - bf2f(h0));
                    unsigned short h1 = f2bf(b[jj]); uh[4+jj] = h1; ul[4+jj] = f2bf(b[jj] - bf2f(h1));
                }
                rh[t2][sv] = uh; rl[t2][sv] = ul;
            }
        }
    #pragma unroll
    for (int t2 = 0; t2 < 2; ++t2)
        #pragma unroll
        for (int sv = 0; sv < 2; ++sv) {
            const int base = (t2 * 8 + w * 2 + sv) * 1024 + lb;
            *(u16x8*)(lds + base) = rh[t2][sv];
            *(u16x8*)(lds + 16384 + base) = rl[t2][sv];
        }
    __syncthreads();

    for (int S = 0; S < NSTEP; ++S) {
        const int b = S & 1;
        if (S + 1 < NSTEP) {
            #pragma unroll
            for (int t2 = 0; t2 < 2; ++t2)
                #pragma unroll
                for (int sv = 0; sv < 2; ++sv) {
                    const int sst = w * 2 + sv;
                    const int code = (S + 1) * 32 + t2 * 16 + nl;
                    if (PRE) {
                        const size_t off = (size_t)code * KDIM + (sst * 4 + g) * 8;
                        rh[t2][sv] = *(const u16x8*)(cb_hi + off);
                        rl[t2][sv] = *(const u16x8*)(cb_lo + off);
                    } else {
                        const float* p = cb + (size_t)code * KDIM + (sst * 4 + g) * 8;
                        f32x4 a = *(const f32x4*)(p);
                        f32x4 bb = *(const f32x4*)(p + 4);
                        u16x8 uh, ul;
                        #pragma unroll
                        for (int jj = 0; jj < 4; ++jj) {
                            unsigned short h0 = f2bf(a[jj]);  uh[jj]   = h0; ul[jj]   = f2bf(a[jj] - bf2f(h0));
                            unsigned short h1 = f2bf(bb[jj]); uh[4+jj] = h1; ul[4+jj] = f2bf(bb[jj] - bf2f(h1));
                        }
                        rh[t2][sv] = uh; rl[t2][sv] = ul;
                    }
                }
        }
        f32x4 cn0 = *(const f32x4*)(cnorm + S * 32 + g * 4);
        f32x4 cn1 = *(const f32x4*)(cnorm + S * 32 + 16 + g * 4);
        {
            const char* buf = lds + b * VBUF;
            #pragma unroll
            for (int t2 = 0; t2 < 2; ++t2) {
                f32x4 acc = {0.f, 0.f, 0.f, 0.f};
                #pragma unroll
                for (int s = 0; s < 8; ++s) {
                    const int base = (t2 * 8 + s) * 1024 + lb;
                    u16x8 ahi = *(const u16x8*)(buf + base);
                    u16x8 alo = *(const u16x8*)(buf + 16384 + base);
                    acc = mfma16(ahi, bhi[s],  acc);
                    acc = mfma16(ahi, bmid[s], acc);
                    acc = mfma16(alo, bhi[s],  acc);
                }
                const f32x4 cn = t2 ? cn1 : cn0;
                #pragma unroll
                for (int r = 0; r < 4; ++r) {
                    const float d2 = cn[r] - 2.0f * acc[r];
                    const int c = S * 32 + t2 * 16 + g * 4 + r;
                    if (d2 < v1)      { v2 = v1; i2 = i1; v1 = d2; i1 = c; }
                    else if (d2 < v2) { v2 = d2; i2 = c; }
                }
            }
        }
        __syncthreads();
        if (S + 1 < NSTEP) {
            char* nbuf = lds + (b ^ 1) * VBUF;
            #pragma unroll
            for (int t2 = 0; t2 < 2; ++t2)
                #pragma unroll
                for (int sv = 0; sv < 2; ++sv) {
                    const int base = (t2 * 8 + w * 2 + sv) * 1024 + lb;
                    *(u16x8*)(nbuf + base) = rh[t2][sv];
                    *(u16x8*)(nbuf + 16384 + base) = rl[t2][sv];
                }
        }
        __syncthreads();
    }

    #pragma unroll
    for (int off = 16; off <= 32; off <<= 1) {
        float ov1 = __shfl_xor(v1, off); int oi1 = __shfl_xor(i1, off);
        float ov2 = __shfl_xor(v2, off); int oi2 = __shfl_xor(i2, off);
        if (ov1 < v1 || (ov1 == v1 && oi1 < i1)) {
            float tv = v1; int ti = i1; v1 = ov1; i1 = oi1; ov1 = tv; oi1 = ti;
            tv = v2; ti = i2; v2 = ov2; i2 = oi2; ov2 = tv; oi2 = ti;
        }
        if (ov1 < v2 || (ov1 == v2 && oi1 < i2)) { v2 = ov1; i2 = oi1; }
    }

    i1 = (i1 < 0) ? 0 : (i1 > NCODES - 1 ? NCODES - 1 : i1);
    i2 = (i2 < 0) ? 0 : (i2 > NCODES - 1 ? NCODES - 1 : i2);

    const float* cp1 = cb + (size_t)i1 * KDIM;
    const float* cp2 = cb + (size_t)i2 * KDIM;
    float da = 0.f, db = 0.f;
    #pragma unroll
    for (int s = 0; s < 8; ++s) {
        f32x4 h0 = *(const f32x4*)(hrow + s * 32 + g * 8);
        f32x4 h1 = *(const f32x4*)(hrow + s * 32 + g * 8 + 4);
        f32x4 a1 = *(const f32x4*)(cp1 + s * 32 + g * 8);
        f32x4 b1 = *(const f32x4*)(cp1 + s * 32 + g * 8 + 4);
        f32x4 a2 = *(const f32x4*)(cp2 + s * 32 + g * 8);
        f32x4 b2 = *(const f32x4*)(cp2 + s * 32 + g * 8 + 4);
        #pragma unroll
        for (int jj = 0; jj < 4; ++jj) {
            da = fmaf(a1[jj], h0[jj], da); da = fmaf(b1[jj], h1[jj], da);
            db = fmaf(a2[jj], h0[jj], db); db = fmaf(b2[jj], h1[jj], db);
        }
    }
    da += __shfl_xor(da, 16); da += __shfl_xor(da, 32);
    db += __shfl_xor(db, 16); db += __shfl_xor(db, 32);
    const float d2a = cnorm[i1] - 2.f * da;
    const float d2b = cnorm[i2] - 2.f * db;
    const int win = (d2a < d2b || (d2a == d2b && i1 < i2)) ? i1 : i2;

    const float* cw = cb + (size_t)win * KDIM;
    #pragma unroll
    for (int s = 0; s < 8; ++s) {
        *(f32x4*)(hrow + s * 32 + g * 8)     = *(const f32x4*)(cw + s * 32 + g * 8);
        *(f32x4*)(hrow + s * 32 + g * 8 + 4) = *(const f32x4*)(cw + s * 32 + g * 8 + 4);
    }
    if (g == 0) idx_out[n0 + row] = (float)win;
}

extern "C" void kernel_launch(void* const* d_in, const int* in_sizes, int n_in,
                              void* d_out, int out_size, void* d_ws, size_t ws_size,
                              hipStream_t stream) {
    (void)in_sizes; (void)n_in; (void)out_size;
    const float* x    = (const float*)d_in[0];
    const float* W    = (const float*)d_in[1];
    const float* bvec = (const float*)d_in[2];
    const float* cb   = (const float*)d_in[3];

    float* codes_out = (float*)d_out;                       // doubles as h buffer
    float* idx_out   = (float*)d_out + (size_t)NROWS * KDIM;

    // ws layout: cnorm[16KB] | recs[512KB, int] | cb_hi[2MB] | cb_lo[2MB] | wt[3x0.5MB]
    float* cnorm = (float*)d_ws;
    int*   recs  = (int*)((char*)d_ws + 16384);
    unsigned short* cb_hi = (unsigned short*)((char*)d_ws + 16384 + 524288);
    unsigned short* cb_lo = cb_hi + (size_t)NCODES * KDIM;
    unsigned short* wt_hi = cb_lo + (size_t)NCODES * KDIM;
    unsigned short* wt_md = wt_hi + (size_t)INDIM * KDIM;
    unsigned short* wt_lo = wt_md + (size_t)INDIM * KDIM;

    const size_t need_rec  = 16384 + 524288;
    const size_t need_cb   = need_rec + (size_t)NCODES * KDIM * 2 * sizeof(unsigned short);
    const size_t need_full = need_cb + (size_t)INDIM * KDIM * 3 * sizeof(unsigned short);

    const int use_split = (ws_size >= need_rec) ? 1 : 0;
    const int pre_cb    = (ws_size >= need_cb) ? 1 : 0;
    const int fast_g    = (ws_size >= need_full) ? 1 : 0;

    if (fast_g) {
        wprep_kernel<<<INDIM / 4, 256, 0, stream>>>(W, wt_hi, wt_md, wt_lo);
        gemm_mfma_kernel<<<NROWS / MG_ROWS, 256, 0, stream>>>(x, wt_hi, wt_md, wt_lo, bvec, codes_out);
    } else {
        gemm_fb_kernel<<<NROWS / G_ROWS, 256, 0, stream>>>(x, W, bvec, codes_out);
    }
    prep_kernel<<<NCODES / 4, 256, 0, stream>>>(cb, cnorm, cb_hi, cb_lo, pre_cb);

    if (use_split) {
        if (pre_cb)
            vq_partial_kernel<1><<<(NROWS / P_ROWS) * 2, 256, 0, stream>>>(codes_out, cb, cnorm, cb_hi, cb_lo, recs);
        else
            vq_partial_kernel<0><<<(NROWS / P_ROWS) * 2, 256, 0, stream>>>(codes_out, cb, cnorm, cb_hi, cb_lo, recs);
        vq_merge_kernel<<<NROWS / V_ROWS, 256, 0, stream>>>(codes_out, cb, cnorm, recs, idx_out);
    } else {
        if (pre_cb)
            vq_kernel<1><<<NROWS / V_ROWS, 256, 0, stream>>>(codes_out, cb, cnorm, cb_hi, cb_lo, idx_out);
        else
            vq_kernel<0><<<NROWS / V_ROWS, 256, 0, stream>>>(codes_out, cb, cnorm, cb_hi, cb_lo, idx_out);
    }
}

// Round 19
// 245.477 us; speedup vs baseline: 1.9875x; 1.1691x over previous
//
#include <hip/hip_runtime.h>

#define NROWS   16384
#define INDIM   1024
#define KDIM    256
#define NCODES  4096
#define G_ROWS  32       // rows per fallback-gemm block
#define V_ROWS  64       // rows per fallback vq / merge block
#define P_ROWS  128      // rows per vq_partial block
#define NSTEP   128      // full-scan vq: steps of 32 codes

// vq LDS: 2 buffers x (hi 16KB + lo 16KB); [t2][s][lane] lane-linear
#define VBUF    32768

// gemm LDS: X 3x8KB ([s][rs][lane]) + W 3x32KB ([s][cidx][lane])
#define MG_ROWS 64
#define MG_KC   64
#define MG_NCH  (INDIM / MG_KC)   // 16
#define XP(p)   ((p) * 8192)
#define WP(p)   (24576 + (p) * 32768)
#define MG_LDS  122880

typedef float f32x4 __attribute__((ext_vector_type(4)));
typedef int   i32x2 __attribute__((ext_vector_type(2)));
typedef short short8 __attribute__((ext_vector_type(8)));
typedef unsigned short u16x8 __attribute__((ext_vector_type(8)));
typedef unsigned short u16x4 __attribute__((ext_vector_type(4)));

__device__ inline unsigned short f2bf(float f) {
    unsigned u = __builtin_bit_cast(unsigned, f);
    u = (u + 0x7fffu + ((u >> 16) & 1u)) >> 16;
    return (unsigned short)u;
}
__device__ inline float bf2f(unsigned short h) {
    unsigned u = ((unsigned)h) << 16;
    return __builtin_bit_cast(float, u);
}
__device__ inline f32x4 mfma16(u16x8 a, u16x8 b, f32x4 c) {
    return __builtin_amdgcn_mfma_f32_16x16x32_bf16(
        __builtin_bit_cast(short8, a), __builtin_bit_cast(short8, b), c, 0, 0, 0);
}

// async global->LDS DMA, 16B/lane; dest = wave-uniform base + lane*16 (HW-implicit)
__device__ inline void gload16(const void* g, void* l) {
    __builtin_amdgcn_global_load_lds(
        (const __attribute__((address_space(1))) unsigned int*)g,
        (__attribute__((address_space(3))) unsigned int*)l,
        16, 0, 0);
}

// ---------------- prep: W[1024][256] f32 -> W_T 3-way bf16 split [256][1024] ----------------
__global__ __launch_bounds__(256) void wprep_kernel(const float* __restrict__ W,
                                                    unsigned short* __restrict__ wt_hi,
                                                    unsigned short* __restrict__ wt_md,
                                                    unsigned short* __restrict__ wt_lo) {
    const int t = threadIdx.x;
    const int k = blockIdx.x * 4 + (t >> 6);
    const int c0 = (t & 63) * 4;
    f32x4 v = *(const f32x4*)(W + (size_t)k * KDIM + c0);
    #pragma unroll
    for (int i = 0; i < 4; ++i) {
        const unsigned short h = f2bf(v[i]);
        const float r1 = v[i] - bf2f(h);
        const unsigned short m = f2bf(r1);
        const unsigned short lo = f2bf(r1 - bf2f(m));
        wt_hi[(size_t)(c0 + i) * INDIM + k] = h;
        wt_md[(size_t)(c0 + i) * INDIM + k] = m;
        wt_lo[(size_t)(c0 + i) * INDIM + k] = lo;
    }
}

// ---------------- MFMA gemm: h = x@W + b (6-pass 3-way split, f32-class accuracy) ----------------
__global__ __launch_bounds__(256, 1) void gemm_mfma_kernel(const float* __restrict__ x,
                                                           const unsigned short* __restrict__ wt_hi,
                                                           const unsigned short* __restrict__ wt_md,
                                                           const unsigned short* __restrict__ wt_lo,
                                                           const float* __restrict__ bvec,
                                                           float* __restrict__ hbuf) {
    __shared__ __align__(16) char lds[MG_LDS];

    const int t  = threadIdx.x;
    const int w  = t >> 6;
    const int l  = t & 63;
    const int nl = l & 15;
    const int g  = l >> 4;
    const size_t n0 = (size_t)blockIdx.x * MG_ROWS;
    const int lb = l * 16;

    f32x4 acc[4][4];
    #pragma unroll
    for (int a = 0; a < 4; ++a)
        #pragma unroll
        for (int b = 0; b < 4; ++b) acc[a][b] = (f32x4){0.f, 0.f, 0.f, 0.f};

    for (int kc = 0; kc < MG_NCH; ++kc) {
        f32x4 xa[2], xb[2];
        #pragma unroll
        for (int c = 0; c < 2; ++c) {
            const int idx = w * 2 + c;
            const int sX = idx >> 2, rsX = idx & 3;
            const float* p = x + (n0 + rsX * 16 + nl) * INDIM + kc * MG_KC + sX * 32 + g * 8;
            xa[c] = *(const f32x4*)(p);
            xb[c] = *(const f32x4*)(p + 4);
        }
        u16x8 wh[8], wm[8], wl[8];
        #pragma unroll
        for (int ci = 0; ci < 4; ++ci)
            #pragma unroll
            for (int sW = 0; sW < 2; ++sW) {
                const int q = ci * 2 + sW;
                const size_t off = (size_t)((w * 4 + ci) * 16 + nl) * INDIM
                                 + kc * MG_KC + sW * 32 + g * 8;
                wh[q] = *(const u16x8*)(wt_hi + off);
                wm[q] = *(const u16x8*)(wt_md + off);
                wl[q] = *(const u16x8*)(wt_lo + off);
            }
        __syncthreads();

        #pragma unroll
        for (int c = 0; c < 2; ++c) {
            const int idx = w * 2 + c;
            const int sX = idx >> 2, rsX = idx & 3;
            u16x8 xh, xm, xl;
            #pragma unroll
            for (int e = 0; e < 4; ++e) {
                const float a0 = xa[c][e], a1 = xb[c][e];
                const unsigned short h0 = f2bf(a0);
                const float r10 = a0 - bf2f(h0);
                const unsigned short m0 = f2bf(r10);
                const unsigned short l0 = f2bf(r10 - bf2f(m0));
                const unsigned short h1 = f2bf(a1);
                const float r11 = a1 - bf2f(h1);
                const unsigned short m1 = f2bf(r11);
                const unsigned short l1 = f2bf(r11 - bf2f(m1));
                xh[e] = h0; xh[4+e] = h1;
                xm[e] = m0; xm[4+e] = m1;
                xl[e] = l0; xl[4+e] = l1;
            }
            const int base = (sX * 4 + rsX) * 1024 + lb;
            *(u16x8*)(lds + XP(0) + base) = xh;
            *(u16x8*)(lds + XP(1) + base) = xm;
            *(u16x8*)(lds + XP(2) + base) = xl;
        }
        #pragma unroll
        for (int ci = 0; ci < 4; ++ci)
            #pragma unroll
            for (int sW = 0; sW < 2; ++sW) {
                const int q = ci * 2 + sW;
                const int base = (sW * 16 + w * 4 + ci) * 1024 + lb;
                *(u16x8*)(lds + WP(0) + base) = wh[q];
                *(u16x8*)(lds + WP(1) + base) = wm[q];
                *(u16x8*)(lds + WP(2) + base) = wl[q];
            }
        __syncthreads();

        #pragma unroll
        for (int s = 0; s < 2; ++s) {
            u16x8 bh[4], bm[4], bl[4], ah[4], am[4], al[4];
            #pragma unroll
            for (int rs = 0; rs < 4; ++rs) {
                const int base = (s * 4 + rs) * 1024 + lb;
                bh[rs] = *(const u16x8*)(lds + XP(0) + base);
                bm[rs] = *(const u16x8*)(lds + XP(1) + base);
                bl[rs] = *(const u16x8*)(lds + XP(2) + base);
            }
            #pragma unroll
            for (int ct = 0; ct < 4; ++ct) {
                const int base = (s * 16 + w * 4 + ct) * 1024 + lb;
                ah[ct] = *(const u16x8*)(lds + WP(0) + base);
                am[ct] = *(const u16x8*)(lds + WP(1) + base);
                al[ct] = *(const u16x8*)(lds + WP(2) + base);
            }
            #pragma unroll
            for (int ct = 0; ct < 4; ++ct)
                #pragma unroll
                for (int rs = 0; rs < 4; ++rs) {
                    acc[ct][rs] = mfma16(ah[ct], bh[rs], acc[ct][rs]);
                    acc[ct][rs] = mfma16(ah[ct], bm[rs], acc[ct][rs]);
                    acc[ct][rs] = mfma16(am[ct], bh[rs], acc[ct][rs]);
                    acc[ct][rs] = mfma16(ah[ct], bl[rs], acc[ct][rs]);
                    acc[ct][rs] = mfma16(al[ct], bh[rs], acc[ct][rs]);
                    acc[ct][rs] = mfma16(am[ct], bm[rs], acc[ct][rs]);
                }
        }
    }

    #pragma unroll
    for (int ct = 0; ct < 4; ++ct) {
        float bv[4];
        #pragma unroll
        for (int r = 0; r < 4; ++r) bv[r] = bvec[w * 64 + ct * 16 + g * 4 + r];
        #pragma unroll
        for (int rs = 0; rs < 4; ++rs) {
            const size_t row = n0 + rs * 16 + nl;
            #pragma unroll
            for (int r = 0; r < 4; ++r)
                hbuf[row * KDIM + w * 64 + ct * 16 + g * 4 + r] = acc[ct][rs][r] + bv[r];
        }
    }
}

// ---------------- fallback f32 gemm ----------------
__global__ __launch_bounds__(256, 2) void gemm_fb_kernel(const float* __restrict__ x,
                                                         const float* __restrict__ W,
                                                         const float* __restrict__ bvec,
                                                         float* __restrict__ hbuf) {
    const int t  = threadIdx.x;
    const int cg = t & 15;
    const int rg = t >> 4;
    const size_t n0 = (size_t)blockIdx.x * G_ROWS;
    const int c0 = cg * 16;

    float acc[2][16];
    #pragma unroll
    for (int j = 0; j < 2; ++j)
        #pragma unroll
        for (int cc = 0; cc < 16; ++cc) acc[j][cc] = 0.f;

    for (int k4 = 0; k4 < INDIM / 4; ++k4) {
        const int k = k4 * 4;
        f32x4 xv[2];
        #pragma unroll
        for (int j = 0; j < 2; ++j)
            xv[j] = *(const f32x4*)(x + (n0 + rg + 16 * j) * INDIM + k);
        f32x4 wv[4][4];
        #pragma unroll
        for (int kk = 0; kk < 4; ++kk)
            #pragma unroll
            for (int q = 0; q < 4; ++q)
                wv[kk][q] = *(const f32x4*)(W + (size_t)(k + kk) * KDIM + c0 + 4 * q);
        #pragma unroll
        for (int j = 0; j < 2; ++j)
            #pragma unroll
            for (int kk = 0; kk < 4; ++kk) {
                const float xs = xv[j][kk];
                #pragma unroll
                for (int q = 0; q < 4; ++q)
                    #pragma unroll
                    for (int e = 0; e < 4; ++e)
                        acc[j][4*q+e] = fmaf(xs, wv[kk][q][e], acc[j][4*q+e]);
            }
    }
    #pragma unroll
    for (int j = 0; j < 2; ++j) {
        float* dst = hbuf + (n0 + rg + 16 * j) * KDIM + c0;
        #pragma unroll
        for (int q = 0; q < 4; ++q) {
            f32x4 v;
            #pragma unroll
            for (int e = 0; e < 4; ++e) v[e] = acc[j][4*q+e] + bvec[c0 + 4*q + e];
            *(f32x4*)(dst + 4*q) = v;
        }
    }
}

// ---------------- prep: cnorm + optional bf16 hi/lo split of cb ----------------
__global__ __launch_bounds__(256) void prep_kernel(const float* __restrict__ cb,
                                                   float* __restrict__ cnorm,
                                                   unsigned short* __restrict__ cb_hi,
                                                   unsigned short* __restrict__ cb_lo,
                                                   int do_split) {
    const int c    = blockIdx.x * 4 + (threadIdx.x >> 6);
    const int lane = threadIdx.x & 63;
    f32x4 v = ((const f32x4*)(cb + (size_t)c * KDIM))[lane];
    if (do_split) {
        u16x4 h4, l4;
        #pragma unroll
        for (int j = 0; j < 4; ++j) {
            unsigned short h = f2bf(v[j]);
            h4[j] = h;
            l4[j] = f2bf(v[j] - bf2f(h));
        }
        *(u16x4*)(cb_hi + (size_t)c * KDIM + lane * 4) = h4;
        *(u16x4*)(cb_lo + (size_t)c * KDIM + lane * 4) = l4;
    }
    float s = v[0]*v[0] + v[1]*v[1] + v[2]*v[2] + v[3]*v[3];
    #pragma unroll
    for (int off = 1; off < 64; off <<= 1) s += __shfl_xor(s, off);
    if (lane == 0) cnorm[c] = s;
}

// ======= vq partial: 128 rows/block, quarter of codes, async gload_lds staging (PRE) ========
template<int PRE>
__global__ __launch_bounds__(256, 2) void vq_partial_kernel(
    const float* __restrict__ hbuf,
    const float* __restrict__ cb,
    const float* __restrict__ cnorm,
    const unsigned short* __restrict__ cb_hi,
    const unsigned short* __restrict__ cb_lo,
    int* __restrict__ recs)                    // [NROWS][4] int2 {i1,i2}
{
    __shared__ __align__(16) char lds[2 * VBUF];

    const int t  = threadIdx.x;
    const int w  = t >> 6;
    const int l  = t & 63;
    const int nl = l & 15;
    const int g  = l >> 4;
    const int lb = l * 16;
    const int bid  = blockIdx.x;
    const int quar = bid & 3;
    const int S0   = quar * 32;
    const size_t n0 = (size_t)(bid >> 2) * P_ROWS;

    // B-fragments for 2 row-sets: rows w*32 + rset*16 + nl
    u16x8 bhi[2][8], bmid[2][8];
    #pragma unroll
    for (int rset = 0; rset < 2; ++rset) {
        const float* hrow = hbuf + (n0 + w * 32 + rset * 16 + nl) * KDIM;
        #pragma unroll
        for (int s = 0; s < 8; ++s) {
            f32x4 a = *(const f32x4*)(hrow + s * 32 + g * 8);
            f32x4 b = *(const f32x4*)(hrow + s * 32 + g * 8 + 4);
            u16x8 uh, um;
            #pragma unroll
            for (int jj = 0; jj < 4; ++jj) {
                unsigned short h0 = f2bf(a[jj]); uh[jj]   = h0; um[jj]   = f2bf(a[jj] - bf2f(h0));
                unsigned short h1 = f2bf(b[jj]); uh[4+jj] = h1; um[4+jj] = f2bf(b[jj] - bf2f(h1));
            }
            bhi[rset][s] = uh; bmid[rset][s] = um;
        }
    }

    float v1[2] = {3.4e38f, 3.4e38f}, v2[2] = {3.4e38f, 3.4e38f};
    int   i1[2] = {0, 0},            i2[2] = {0, 0};

    u16x8 rh[2][2], rl[2][2];   // used only by non-PRE path

    // ---- prologue: stage step S0 into buffer 0 ----
    if (PRE) {
        #pragma unroll
        for (int t2 = 0; t2 < 2; ++t2)
            #pragma unroll
            for (int sv = 0; sv < 2; ++sv) {
                const int sst = w * 2 + sv;
                const int code = S0 * 32 + t2 * 16 + nl;
                const size_t off = (size_t)code * KDIM + (sst * 4 + g) * 8;
                const int base = (t2 * 8 + w * 2 + sv) * 1024;   // wave-uniform; HW adds lane*16
                gload16(cb_hi + off, lds + base);
                gload16(cb_lo + off, lds + 16384 + base);
            }
    } else {
        #pragma unroll
        for (int t2 = 0; t2 < 2; ++t2)
            #pragma unroll
            for (int sv = 0; sv < 2; ++sv) {
                const int sst = w * 2 + sv;
                const int code = S0 * 32 + t2 * 16 + nl;
                const float* p = cb + (size_t)code * KDIM + (sst * 4 + g) * 8;
                f32x4 a = *(const f32x4*)(p);
                f32x4 b = *(const f32x4*)(p + 4);
                u16x8 uh, ul;
                #pragma unroll
                for (int jj = 0; jj < 4; ++jj) {
                    unsigned short h0 = f2bf(a[jj]); uh[jj]   = h0; ul[jj]   = f2bf(a[jj] - bf2f(h0));
                    unsigned short h1 = f2bf(b[jj]); uh[4+jj] = h1; ul[4+jj] = f2bf(b[jj] - bf2f(h1));
                }
                rh[t2][sv] = uh; rl[t2][sv] = ul;
            }
        #pragma unroll
        for (int t2 = 0; t2 < 2; ++t2)
            #pragma unroll
            for (int sv = 0; sv < 2; ++sv) {
                const int base = (t2 * 8 + w * 2 + sv) * 1024 + lb;
                *(u16x8*)(lds + base) = rh[t2][sv];
                *(u16x8*)(lds + 16384 + base) = rl[t2][sv];
            }
    }
    __syncthreads();

    for (int S = S0; S < S0 + 32; ++S) {
        const int b = S & 1;
        char* nbuf = lds + (b ^ 1) * VBUF;
        if (S + 1 < S0 + 32) {
            if (PRE) {
                // async DMA for next step into back buffer; drained by the barrier below
                #pragma unroll
                for (int t2 = 0; t2 < 2; ++t2)
                    #pragma unroll
                    for (int sv = 0; sv < 2; ++sv) {
                        const int sst = w * 2 + sv;
                        const int code = (S + 1) * 32 + t2 * 16 + nl;
                        const size_t off = (size_t)code * KDIM + (sst * 4 + g) * 8;
                        const int base = (t2 * 8 + w * 2 + sv) * 1024;
                        gload16(cb_hi + off, nbuf + base);
                        gload16(cb_lo + off, nbuf + 16384 + base);
                    }
            } else {
                #pragma unroll
                for (int t2 = 0; t2 < 2; ++t2)
                    #pragma unroll
                    for (int sv = 0; sv < 2; ++sv) {
                        const int sst = w * 2 + sv;
                        const int code = (S + 1) * 32 + t2 * 16 + nl;
                        const float* p = cb + (size_t)code * KDIM + (sst * 4 + g) * 8;
                        f32x4 a = *(const f32x4*)(p);
                        f32x4 bb = *(const f32x4*)(p + 4);
                        u16x8 uh, ul;
                        #pragma unroll
                        for (int jj = 0; jj < 4; ++jj) {
                            unsigned short h0 = f2bf(a[jj]);  uh[jj]   = h0; ul[jj]   = f2bf(a[jj] - bf2f(h0));
                            unsigned short h1 = f2bf(bb[jj]); uh[4+jj] = h1; ul[4+jj] = f2bf(bb[jj] - bf2f(h1));
                        }
                        rh[t2][sv] = uh; rl[t2][sv] = ul;
                    }
            }
        }
        f32x4 cn0 = *(const f32x4*)(cnorm + S * 32 + g * 4);
        f32x4 cn1 = *(const f32x4*)(cnorm + S * 32 + 16 + g * 4);
        {
            const char* buf = lds + b * VBUF;
            #pragma unroll
            for (int t2 = 0; t2 < 2; ++t2) {
                f32x4 acc0 = {0.f, 0.f, 0.f, 0.f};
                f32x4 acc1 = {0.f, 0.f, 0.f, 0.f};
                #pragma unroll
                for (int s = 0; s < 8; ++s) {
                    const int base = (t2 * 8 + s) * 1024 + lb;
                    u16x8 ahi = *(const u16x8*)(buf + base);
                    u16x8 alo = *(const u16x8*)(buf + 16384 + base);
                    acc0 = mfma16(ahi, bhi[0][s],  acc0);
                    acc0 = mfma16(ahi, bmid[0][s], acc0);
                    acc0 = mfma16(alo, bhi[0][s],  acc0);
                    acc1 = mfma16(ahi, bhi[1][s],  acc1);
                    acc1 = mfma16(ahi, bmid[1][s], acc1);
                    acc1 = mfma16(alo, bhi[1][s],  acc1);
                }
                const f32x4 cn = t2 ? cn1 : cn0;
                #pragma unroll
                for (int r = 0; r < 4; ++r) {
                    const int c = S * 32 + t2 * 16 + g * 4 + r;
                    const float d0 = cn[r] - 2.0f * acc0[r];
                    if (d0 < v1[0])      { v2[0] = v1[0]; i2[0] = i1[0]; v1[0] = d0; i1[0] = c; }
                    else if (d0 < v2[0]) { v2[0] = d0; i2[0] = c; }
                    const float d1 = cn[r] - 2.0f * acc1[r];
                    if (d1 < v1[1])      { v2[1] = v1[1]; i2[1] = i1[1]; v1[1] = d1; i1[1] = c; }
                    else if (d1 < v2[1]) { v2[1] = d1; i2[1] = c; }
                }
            }
        }
        __syncthreads();   // PRE: drains DMA (back buffer ready) + read-sync; non-PRE: read-sync
        if (!PRE) {
            if (S + 1 < S0 + 32) {
                #pragma unroll
                for (int t2 = 0; t2 < 2; ++t2)
                    #pragma unroll
                    for (int sv = 0; sv < 2; ++sv) {
                        const int base = (t2 * 8 + w * 2 + sv) * 1024 + lb;
                        *(u16x8*)(nbuf + base) = rh[t2][sv];
                        *(u16x8*)(nbuf + 16384 + base) = rl[t2][sv];
                    }
            }
            __syncthreads();
        }
    }

    // merge top-2 across the 4 g-lane-groups for each row-set
    #pragma unroll
    for (int rset = 0; rset < 2; ++rset) {
        #pragma unroll
        for (int off = 16; off <= 32; off <<= 1) {
            float ov1 = __shfl_xor(v1[rset], off); int oi1 = __shfl_xor(i1[rset], off);
            float ov2 = __shfl_xor(v2[rset], off); int oi2 = __shfl_xor(i2[rset], off);
            if (ov1 < v1[rset] || (ov1 == v1[rset] && oi1 < i1[rset])) {
                float tv = v1[rset]; int ti = i1[rset]; v1[rset] = ov1; i1[rset] = oi1; ov1 = tv; oi1 = ti;
                tv = v2[rset]; ti = i2[rset]; v2[rset] = ov2; i2[rset] = oi2; ov2 = tv; oi2 = ti;
            }
            if (ov1 < v2[rset] || (ov1 == v2[rset] && oi1 < i2[rset])) { v2[rset] = ov1; i2[rset] = oi1; }
        }
    }

    // write 8B index-pair record at [row][quar] (int-typed memory — proven-safe path)
    if (g == 0) {
        #pragma unroll
        for (int rset = 0; rset < 2; ++rset) {
            i32x2 rec;
            rec[0] = i1[rset]; rec[1] = i2[rset];
            const size_t row = n0 + w * 32 + rset * 16 + nl;
            *(i32x2*)(recs + (row * 4 + quar) * 2) = rec;
        }
    }
}

// ====== vq merge: exact-refine ALL 8 candidates (4 quarters x top-2), gather, idx ===========
__global__ __launch_bounds__(256) void vq_merge_kernel(
    float* __restrict__ hbuf,
    const float* __restrict__ cb,
    const float* __restrict__ cnorm,
    const int* __restrict__ recs,
    float* __restrict__ idx_out)
{
    const int t  = threadIdx.x;
    const int w  = t >> 6;
    const int l  = t & 63;
    const int nl = l & 15;
    const int g  = l >> 4;
    const size_t n0 = (size_t)blockIdx.x * V_ROWS;
    const int row = w * 16 + nl;
    float* hrow = hbuf + (n0 + row) * KDIM;

    int cand[8];
    {
        const size_t rb = (n0 + row) * 8;
        #pragma unroll
        for (int q = 0; q < 4; ++q) {
            i32x2 rq = *(const i32x2*)(recs + rb + q * 2);
            int a = rq[0], b = rq[1];
            cand[2*q]   = (a < 0) ? 0 : (a > NCODES - 1 ? NCODES - 1 : a);
            cand[2*q+1] = (b < 0) ? 0 : (b > NCODES - 1 ? NCODES - 1 : b);
        }
    }

    f32x4 hreg[16];
    #pragma unroll
    for (int s = 0; s < 8; ++s) {
        hreg[2*s]   = *(const f32x4*)(hrow + s * 32 + g * 8);
        hreg[2*s+1] = *(const f32x4*)(hrow + s * 32 + g * 8 + 4);
    }

    float bestd = 3.4e38f;
    int   besti = 0x7fffffff;
    #pragma unroll
    for (int k = 0; k < 8; ++k) {
        const int ci = cand[k];
        const float* cp = cb + (size_t)ci * KDIM;
        float d = 0.f;
        #pragma unroll
        for (int s = 0; s < 8; ++s) {
            f32x4 a = *(const f32x4*)(cp + s * 32 + g * 8);
            f32x4 b = *(const f32x4*)(cp + s * 32 + g * 8 + 4);
            #pragma unroll
            for (int jj = 0; jj < 4; ++jj) {
                d = fmaf(a[jj], hreg[2*s][jj], d);
                d = fmaf(b[jj], hreg[2*s+1][jj], d);
            }
        }
        d += __shfl_xor(d, 16); d += __shfl_xor(d, 32);
        const float d2 = cnorm[ci] - 2.f * d;
        if (d2 < bestd || (d2 == bestd && ci < besti)) { bestd = d2; besti = ci; }
    }

    const float* cw = cb + (size_t)besti * KDIM;
    #pragma unroll
    for (int s = 0; s < 8; ++s) {
        *(f32x4*)(hrow + s * 32 + g * 8)     = *(const f32x4*)(cw + s * 32 + g * 8);
        *(f32x4*)(hrow + s * 32 + g * 8 + 4) = *(const f32x4*)(cw + s * 32 + g * 8 + 4);
    }
    if (g == 0) idx_out[n0 + row] = (float)besti;
}

// ---------------- r7-proven full-scan vq (fallback when ws too small for records) -----------
template<int PRE>
__global__ __launch_bounds__(256) void vq_kernel(
    float* __restrict__ hbuf,
    const float* __restrict__ cb,
    const float* __restrict__ cnorm,
    const unsigned short* __restrict__ cb_hi,
    const unsigned short* __restrict__ cb_lo,
    float* __restrict__ idx_out)
{
    __shared__ __align__(16) char lds[2 * VBUF];

    const int t  = threadIdx.x;
    const int w  = t >> 6;
    const int l  = t & 63;
    const int nl = l & 15;
    const int g  = l >> 4;
    const int lb = l * 16;
    const size_t n0 = (size_t)blockIdx.x * V_ROWS;
    const int row = w * 16 + nl;
    float* hrow = hbuf + (n0 + row) * KDIM;

    u16x8 bhi[8], bmid[8];
    #pragma unroll
    for (int s = 0; s < 8; ++s) {
        f32x4 a = *(const f32x4*)(hrow + s * 32 + g * 8);
        f32x4 b = *(const f32x4*)(hrow + s * 32 + g * 8 + 4);
        u16x8 uh, um;
        #pragma unroll
        for (int jj = 0; jj < 4; ++jj) {
            unsigned short h0 = f2bf(a[jj]); uh[jj]   = h0; um[jj]   = f2bf(a[jj] - bf2f(h0));
            unsigned short h1 = f2bf(b[jj]); uh[4+jj] = h1; um[4+jj] = f2bf(b[jj] - bf2f(h1));
        }
        bhi[s] = uh; bmid[s] = um;
    }

    float v1 = 3.4e38f, v2 = 3.4e38f;
    int   i1 = 0, i2 = 0;

    u16x8 rh[2][2], rl[2][2];

    #pragma unroll
    for (int t2 = 0; t2 < 2; ++t2)
        #pragma unroll
        for (int sv = 0; sv < 2; ++sv) {
            const int sst = w * 2 + sv;
            if (PRE) {
                const size_t off = (size_t)(t2 * 16 + nl) * KDIM + (sst * 4 + g) * 8;
                rh[t2][sv] = *(const u16x8*)(cb_hi + off);
                rl[t2][sv] = *(const u16x8*)(cb_lo + off);
            } else {
                const float* p = cb + (size_t)(t2 * 16 + nl) * KDIM + (sst * 4 + g) * 8;
                f32x4 a = *(const f32x4*)(p);
                f32x4 b = *(const f32x4*)(p + 4);
                u16x8 uh, ul;
                #pragma unroll
                for (int jj = 0; jj < 4; ++jj) {
                    unsigned short h0 = f2bf(a[jj]); uh[jj]   = h0; ul[jj]   = f2bf(a[jj] - bf2f(h0));
                    unsigned short h1 = f2bf(b[jj]); uh[4+jj] = h1; ul[4+jj] = f2bf(b[jj] - bf2f(h1));
                }
                rh[t2][sv] = uh; rl[t2][sv] = ul;
            }
        }
    #pragma unroll
    for (int t2 = 0; t2 < 2; ++t2)
        #pragma unroll
        for (int sv = 0; sv < 2; ++sv) {
            const int base = (t2 * 8 + w * 2 + sv) * 1024 + lb;
            *(u16x8*)(lds + base) = rh[t2][sv];
            *(u16x8*)(lds + 16384 + base) = rl[t2][sv];
        }
    __syncthreads();

    for (int S = 0; S < NSTEP; ++S) {
        const int b = S & 1;
        if (S + 1 < NSTEP) {
            #pragma unroll
            for (int t2 = 0; t2 < 2; ++t2)
                #pragma unroll
                for (int sv = 0; sv < 2; ++sv) {
                    const int sst = w * 2 + sv;
                    const int code = (S + 1) * 32 + t2 * 16 + nl;
                    if (PRE) {
                        const size_t off = (size_t)code * KDIM + (sst * 4 + g) * 8;
                        rh[t2][sv] = *(const u16x8*)(cb_hi + off);
                        rl[t2][sv] = *(const u16x8*)(cb_lo + off);
                    } else {
                        const float* p = cb + (size_t)code * KDIM + (sst * 4 + g) * 8;
                        f32x4 a = *(const f32x4*)(p);
                        f32x4 bb = *(const f32x4*)(p + 4);
                        u16x8 uh, ul;
                        #pragma unroll
                        for (int jj = 0; jj < 4; ++jj) {
                            unsigned short h0 = f2bf(a[jj]);  uh[jj]   = h0; ul[jj]   = f2bf(a[jj] - bf2f(h0));
                            unsigned short h1 = f2bf(bb[jj]); uh[4+jj] = h1; ul[4+jj] = f2bf(bb[jj] - bf2f(h1));
                        }
                        rh[t2][sv] = uh; rl[t2][sv] = ul;
                    }
                }
        }
        f32x4 cn0 = *(const f32x4*)(cnorm + S * 32 + g * 4);
        f32x4 cn1 = *(const f32x4*)(cnorm + S * 32 + 16 + g * 4);
        {
            const char* buf = lds + b * VBUF;
            #pragma unroll
            for (int t2 = 0; t2 < 2; ++t2) {
                f32x4 acc = {0.f, 0.f, 0.f, 0.f};
                #pragma unroll
                for (int s = 0; s < 8; ++s) {
                    const int base = (t2 * 8 + s) * 1024 + lb;
                    u16x8 ahi = *(const u16x8*)(buf + base);
                    u16x8 alo = *(const u16x8*)(buf + 16384 + base);
                    acc = mfma16(ahi, bhi[s],  acc);
                    acc = mfma16(ahi, bmid[s], acc);
                    acc = mfma16(alo, bhi[s],  acc);
                }
                const f32x4 cn = t2 ? cn1 : cn0;
                #pragma unroll
                for (int r = 0; r < 4; ++r) {
                    const float d2 = cn[r] - 2.0f * acc[r];
                    const int c = S * 32 + t2 * 16 + g * 4 + r;
                    if (d2 < v1)      { v2 = v1; i2 = i1; v1 = d2; i1 = c; }
                    else if (d2 < v2) { v2 = d2; i2 = c; }
                }
            }
        }
        __syncthreads();
        if (S + 1 < NSTEP) {
            char* nbuf = lds + (b ^ 1) * VBUF;
            #pragma unroll
            for (int t2 = 0; t2 < 2; ++t2)
                #pragma unroll
                for (int sv = 0; sv < 2; ++sv) {
                    const int base = (t2 * 8 + w * 2 + sv) * 1024 + lb;
                    *(u16x8*)(nbuf + base) = rh[t2][sv];
                    *(u16x8*)(nbuf + 16384 + base) = rl[t2][sv];
                }
        }
        __syncthreads();
    }

    #pragma unroll
    for (int off = 16; off <= 32; off <<= 1) {
        float ov1 = __shfl_xor(v1, off); int oi1 = __shfl_xor(i1, off);
        float ov2 = __shfl_xor(v2, off); int oi2 = __shfl_xor(i2, off);
        if (ov1 < v1 || (ov1 == v1 && oi1 < i1)) {
            float tv = v1; int ti = i1; v1 = ov1; i1 = oi1; ov1 = tv; oi1 = ti;
            tv = v2; ti = i2; v2 = ov2; i2 = oi2; ov2 = tv; oi2 = ti;
        }
        if (ov1 < v2 || (ov1 == v2 && oi1 < i2)) { v2 = ov1; i2 = oi1; }
    }

    i1 = (i1 < 0) ? 0 : (i1 > NCODES - 1 ? NCODES - 1 : i1);
    i2 = (i2 < 0) ? 0 : (i2 > NCODES - 1 ? NCODES - 1 : i2);

    const float* cp1 = cb + (size_t)i1 * KDIM;
    const float* cp2 = cb + (size_t)i2 * KDIM;
    float da = 0.f, db = 0.f;
    #pragma unroll
    for (int s = 0; s < 8; ++s) {
        f32x4 h0 = *(const f32x4*)(hrow + s * 32 + g * 8);
        f32x4 h1 = *(const f32x4*)(hrow + s * 32 + g * 8 + 4);
        f32x4 a1 = *(const f32x4*)(cp1 + s * 32 + g * 8);
        f32x4 b1 = *(const f32x4*)(cp1 + s * 32 + g * 8 + 4);
        f32x4 a2 = *(const f32x4*)(cp2 + s * 32 + g * 8);
        f32x4 b2 = *(const f32x4*)(cp2 + s * 32 + g * 8 + 4);
        #pragma unroll
        for (int jj = 0; jj < 4; ++jj) {
            da = fmaf(a1[jj], h0[jj], da); da = fmaf(b1[jj], h1[jj], da);
            db = fmaf(a2[jj], h0[jj], db); db = fmaf(b2[jj], h1[jj], db);
        }
    }
    da += __shfl_xor(da, 16); da += __shfl_xor(da, 32);
    db += __shfl_xor(db, 16); db += __shfl_xor(db, 32);
    const float d2a = cnorm[i1] - 2.f * da;
    const float d2b = cnorm[i2] - 2.f * db;
    const int win = (d2a < d2b || (d2a == d2b && i1 < i2)) ? i1 : i2;

    const float* cw = cb + (size_t)win * KDIM;
    #pragma unroll
    for (int s = 0; s < 8; ++s) {
        *(f32x4*)(hrow + s * 32 + g * 8)     = *(const f32x4*)(cw + s * 32 + g * 8);
        *(f32x4*)(hrow + s * 32 + g * 8 + 4) = *(const f32x4*)(cw + s * 32 + g * 8 + 4);
    }
    if (g == 0) idx_out[n0 + row] = (float)win;
}

extern "C" void kernel_launch(void* const* d_in, const int* in_sizes, int n_in,
                              void* d_out, int out_size, void* d_ws, size_t ws_size,
                              hipStream_t stream) {
    (void)in_sizes; (void)n_in; (void)out_size;
    const float* x    = (const float*)d_in[0];
    const float* W    = (const float*)d_in[1];
    const float* bvec = (const float*)d_in[2];
    const float* cb   = (const float*)d_in[3];

    float* codes_out = (float*)d_out;                       // doubles as h buffer
    float* idx_out   = (float*)d_out + (size_t)NROWS * KDIM;

    // ws layout: cnorm[16KB] | recs[512KB, int] | cb_hi[2MB] | cb_lo[2MB] | wt[3x0.5MB]
    float* cnorm = (float*)d_ws;
    int*   recs  = (int*)((char*)d_ws + 16384);
    unsigned short* cb_hi = (unsigned short*)((char*)d_ws + 16384 + 524288);
    unsigned short* cb_lo = cb_hi + (size_t)NCODES * KDIM;
    unsigned short* wt_hi = cb_lo + (size_t)NCODES * KDIM;
    unsigned short* wt_md = wt_hi + (size_t)INDIM * KDIM;
    unsigned short* wt_lo = wt_md + (size_t)INDIM * KDIM;

    const size_t need_rec  = 16384 + 524288;
    const size_t need_cb   = need_rec + (size_t)NCODES * KDIM * 2 * sizeof(unsigned short);
    const size_t need_full = need_cb + (size_t)INDIM * KDIM * 3 * sizeof(unsigned short);

    const int use_split = (ws_size >= need_rec) ? 1 : 0;
    const int pre_cb    = (ws_size >= need_cb) ? 1 : 0;
    const int fast_g    = (ws_size >= need_full) ? 1 : 0;

    if (fast_g) {
        wprep_kernel<<<INDIM / 4, 256, 0, stream>>>(W, wt_hi, wt_md, wt_lo);
        gemm_mfma_kernel<<<NROWS / MG_ROWS, 256, 0, stream>>>(x, wt_hi, wt_md, wt_lo, bvec, codes_out);
    } else {
        gemm_fb_kernel<<<NROWS / G_ROWS, 256, 0, stream>>>(x, W, bvec, codes_out);
    }
    prep_kernel<<<NCODES / 4, 256, 0, stream>>>(cb, cnorm, cb_hi, cb_lo, pre_cb);

    if (use_split) {
        if (pre_cb)
            vq_partial_kernel<1><<<(NROWS / P_ROWS) * 4, 256, 0, stream>>>(codes_out, cb, cnorm, cb_hi, cb_lo, recs);
        else
            vq_partial_kernel<0><<<(NROWS / P_ROWS) * 4, 256, 0, stream>>>(codes_out, cb, cnorm, cb_hi, cb_lo, recs);
        vq_merge_kernel<<<NROWS / V_ROWS, 256, 0, stream>>>(codes_out, cb, cnorm, recs, idx_out);
    } else {
        if (pre_cb)
            vq_kernel<1><<<NROWS / V_ROWS, 256, 0, stream>>>(codes_out, cb, cnorm, cb_hi, cb_lo, idx_out);
        else
            vq_kernel<0><<<NROWS / V_ROWS, 256, 0, stream>>>(codes_out, cb, cnorm, cb_hi, cb_lo, idx_out);
    }
}